// Round 1
// baseline (1504.375 us; speedup 1.0000x reference)
//
#include <hip/hip_runtime.h>
#include <hip/hip_bf16.h>

#define NB 16
#define ND 256
#define NL 1024
#define NHH 8
#define NDK 32
#define NKW 7
#define NCONV 4
#define NPB (ND*NL)   // 262144 elements per batch item for LN

constexpr float LN_EPS = 1e-5f;

// ---------------- LN helpers ----------------
__device__ __forceinline__ void ln_ab(const float* st, int slot, int b, float& mean, float& rstd){
  float s  = st[(slot*NB + b)*2];
  float ss = st[(slot*NB + b)*2 + 1];
  mean = s * (1.0f/NPB);
  float var = ss * (1.0f/NPB) - mean*mean;
  rstd = rsqrtf(var + LN_EPS);
}

__device__ __forceinline__ void stats_reduce(float s, float ss, float* stats, int slot, int b){
  __shared__ float red[8];
  #pragma unroll
  for(int o=32;o>0;o>>=1){ s += __shfl_down(s,o); ss += __shfl_down(ss,o); }
  int lane = threadIdx.x & 63, w = threadIdx.x >> 6;
  if(lane==0){ red[w*2]=s; red[w*2+1]=ss; }
  __syncthreads();
  if(threadIdx.x==0){
    atomicAdd(&stats[(slot*NB+b)*2],   red[0]+red[2]+red[4]+red[6]);
    atomicAdd(&stats[(slot*NB+b)*2+1], red[1]+red[3]+red[5]+red[7]);
  }
}

// ---------------- positional encoding table (D x L) ----------------
__global__ __launch_bounds__(256) void k_pos(float* __restrict__ pos){
  int idx = blockIdx.x*256 + threadIdx.x;
  int d = idx >> 10, l = idx & (NL-1);
  float fd = (float)d;
  const float LN1E4_OVER_D = 9.210340371976184f / (float)ND;
  float freq, phase;
  if((d & 1) == 0){ freq =  __expf(-fd*LN1E4_OVER_D);      phase = 0.f; }
  else            { freq = -__expf((1.f-fd)*LN1E4_OVER_D); phase = 1.5707963267948966f; }
  pos[idx] = sinf((float)l * freq + phase);
}

// ---------------- x + pos, accumulate LN0 stats ----------------
__global__ __launch_bounds__(256) void k_posadd(const float* __restrict__ x, const float* __restrict__ pos,
                                                float* __restrict__ R, float* __restrict__ stats){
  int idx = blockIdx.x*256 + threadIdx.x;
  int b = idx >> 18;            // D*L = 2^18
  int dl = idx & (NPB-1);
  float v = x[idx] + pos[dl];
  R[idx] = v;
  stats_reduce(v, v*v, stats, 0, b);
}

// ---------------- depthwise conv (LN applied on the fly) ----------------
__global__ __launch_bounds__(256) void k_dwconv(const float* __restrict__ R, const float* __restrict__ g,
                                                const float* __restrict__ bt, const float* __restrict__ w7,
                                                const float* __restrict__ b1, const float* __restrict__ stats,
                                                float* __restrict__ out, int slot){
  int blk = blockIdx.x;
  int l0 = (blk & 3) << 8;           // L/256 = 4 segments
  int d  = (blk >> 2) & (ND-1);
  int b  = blk >> 10;
  float mean, rstd; ln_ab(stats, slot, b, mean, rstd);
  __shared__ float tile[256 + NKW - 1];
  int rowoff = ((b*ND + d) << 10);
  int goff   = d << 10;
  for(int j = threadIdx.x; j < 256 + NKW - 1; j += 256){
    int l = l0 - (NKW/2) + j;
    float v = 0.f;
    if(l >= 0 && l < NL){
      v = (R[rowoff + l] - mean) * rstd * g[goff + l] + bt[goff + l];
    }
    tile[j] = v;
  }
  __syncthreads();
  float acc = b1[d];
  #pragma unroll
  for(int q=0;q<NKW;q++) acc += tile[threadIdx.x + q] * w7[d*NKW + q];
  out[rowoff + l0 + threadIdx.x] = acc;
}

// ---------------- pointwise conv GEMM: R = relu(W*In + bias) + R, stats ----------------
__global__ __launch_bounds__(256) void k_pw(const float* __restrict__ In, const float* __restrict__ W,
                                            const float* __restrict__ bias, float* __restrict__ R,
                                            float* __restrict__ stats, int slot_out){
  int blk = blockIdx.x;
  int l0 = (blk & 15) << 6;
  int e0 = ((blk >> 4) & 3) << 6;
  int b  = blk >> 6;
  int tid = threadIdx.x;
  int tx = tid & 15, ty = tid >> 4;     // tx->l, ty->e
  __shared__ float As[16][65];          // [kk][ee] weights (padded)
  __shared__ float Bs[16][64];          // [kk][ll] input
  float acc[4][4] = {};
  for(int d0=0; d0<ND; d0+=16){
    __syncthreads();
    {
      int f = tid << 2;
      int ee = f >> 4, kk = f & 15;
      const float* wp = W + (e0+ee)*ND + d0 + kk;
      #pragma unroll
      for(int j=0;j<4;j++) As[kk+j][ee] = wp[j];
    }
    {
      int f = tid << 2;
      int kk = f >> 6, ll = f & 63;
      const float* ip = In + ((b*ND + d0 + kk) << 10) + l0 + ll;
      #pragma unroll
      for(int j=0;j<4;j++) Bs[kk][ll+j] = ip[j];
    }
    __syncthreads();
    #pragma unroll
    for(int kk=0;kk<16;kk++){
      float a[4], c[4];
      #pragma unroll
      for(int i=0;i<4;i++) a[i] = As[kk][ty + 16*i];
      #pragma unroll
      for(int j=0;j<4;j++) c[j] = Bs[kk][tx + 16*j];
      #pragma unroll
      for(int i=0;i<4;i++)
        #pragma unroll
        for(int j=0;j<4;j++) acc[i][j] += a[i]*c[j];
    }
  }
  float s=0.f, ss=0.f;
  #pragma unroll
  for(int i=0;i<4;i++){
    int e = e0 + ty + 16*i;
    float bv = bias[e];
    int base = ((b*ND + e) << 10) + l0 + tx;
    #pragma unroll
    for(int j=0;j<4;j++){
      float v = fmaxf(acc[i][j] + bv, 0.f);
      float r = R[base + 16*j] + v;
      R[base + 16*j] = r;
      s += r; ss += r*r;
    }
  }
  stats_reduce(s, ss, stats, slot_out, b);
}

// ---------------- QKV projection GEMM (LN4 fused): out[b][l][h*32+k] ----------------
__global__ __launch_bounds__(256) void k_qkv(const float* __restrict__ R, const float* __restrict__ g,
                                             const float* __restrict__ bt, const float* __restrict__ stats,
                                             const float* __restrict__ Wh, float* __restrict__ out){
  int blk = blockIdx.x;
  int l0 = (blk & 15) << 6;
  int o0 = ((blk >> 4) & 3) << 6;
  int b  = blk >> 6;
  int tid = threadIdx.x;
  int tx = tid & 15, ty = tid >> 4;     // tx->o, ty->l
  float mean, rstd; ln_ab(stats, 4, b, mean, rstd);
  __shared__ float As[16][64];          // [kk][ll] normalized input
  __shared__ float Bs[16][64];          // [kk][oo] weight
  float acc[4][4] = {};
  for(int d0=0; d0<ND; d0+=16){
    __syncthreads();
    {
      int f = tid << 2;
      int kk = f >> 6, ll = f & 63;
      int gbase = ((d0+kk) << 10) + l0 + ll;
      const float* ip = R + (b << 18) + gbase;
      #pragma unroll
      for(int j=0;j<4;j++) As[kk][ll+j] = (ip[j] - mean)*rstd*g[gbase+j] + bt[gbase+j];
    }
    {
      int f = tid << 2;
      int kk = f >> 6, oo = f & 63;
      int o = o0 + oo;
      int h = o >> 5, k = o & 31;
      const float* wp = Wh + (h*ND + d0 + kk)*NDK + k;
      #pragma unroll
      for(int j=0;j<4;j++) Bs[kk][oo+j] = wp[j];
    }
    __syncthreads();
    #pragma unroll
    for(int kk=0;kk<16;kk++){
      float a[4], c[4];
      #pragma unroll
      for(int i=0;i<4;i++) a[i] = As[kk][ty + 16*i];
      #pragma unroll
      for(int j=0;j<4;j++) c[j] = Bs[kk][tx + 16*j];
      #pragma unroll
      for(int i=0;i<4;i++)
        #pragma unroll
        for(int j=0;j<4;j++) acc[i][j] += a[i]*c[j];
    }
  }
  #pragma unroll
  for(int i=0;i<4;i++){
    int l = l0 + ty + 16*i;
    float* op = out + (b*NL + l)*(NHH*NDK) + o0 + tx;
    #pragma unroll
    for(int j=0;j<4;j++) op[16*j] = acc[i][j];
  }
}

// ---------------- flash-style attention: one thread = one query row ----------------
__global__ __launch_bounds__(256) void k_attn(const float* __restrict__ Q, const float* __restrict__ Kb,
                                              const float* __restrict__ Vb, const int* __restrict__ mask,
                                              float* __restrict__ heads){
  int blk = blockIdx.x;
  int qseg = (blk & 3) << 8;
  int h = (blk >> 2) & 7;
  int b = blk >> 5;
  int l = qseg + threadIdx.x;
  float q[32];
  const float* qp = Q + (b*NL + l)*(NHH*NDK) + h*NDK;
  #pragma unroll
  for(int k=0;k<32;k++) q[k] = qp[k] * 0.17677669529663687f;   // 1/sqrt(32)
  float acc[32];
  #pragma unroll
  for(int k=0;k<32;k++) acc[k] = 0.f;
  float denom = 0.f;
  __shared__ float Ks[64][32];
  __shared__ float Vs[64][32];
  __shared__ float ms[64];
  for(int t0=0; t0<NL; t0+=64){
    __syncthreads();
    for(int f = threadIdx.x; f < 64*32; f += 256){
      int i = f >> 5, k = f & 31;
      int gi = (b*NL + t0 + i)*(NHH*NDK) + h*NDK + k;
      Ks[i][k] = Kb[gi];
      Vs[i][k] = Vb[gi];
    }
    if(threadIdx.x < 64) ms[threadIdx.x] = (float)mask[b*NL + t0 + threadIdx.x];
    __syncthreads();
    for(int i=0;i<64;i++){
      float s = 0.f;
      #pragma unroll
      for(int k=0;k<32;k++) s += q[k]*Ks[i][k];
      float mv = ms[i];
      s = s*mv + (1.f-mv)*(-1e30f);
      float p = expf(s);     // scores are O(1); masked -> exp(-1e30)=0 exactly
      denom += p;
      #pragma unroll
      for(int k=0;k<32;k++) acc[k] += p * Vs[i][k];
    }
  }
  float mq = (float)mask[b*NL + l];
  float inv = mq / denom;
  float* op = heads + (b*NL + l)*(NHH*NDK) + h*NDK;
  #pragma unroll
  for(int k=0;k<32;k++) op[k] = acc[k]*inv;
}

// ---------------- output projection: R += heads @ Wo, stats slot 5 ----------------
__global__ __launch_bounds__(256) void k_wo(const float* __restrict__ heads, const float* __restrict__ Wo,
                                            float* __restrict__ R, float* __restrict__ stats){
  int blk = blockIdx.x;
  int l0 = (blk & 15) << 6;
  int e0 = ((blk >> 4) & 3) << 6;
  int b  = blk >> 6;
  int tid = threadIdx.x;
  int tx = tid & 15, ty = tid >> 4;     // tx->l, ty->e
  __shared__ float As[16][64];          // [kk][ee] Wo
  __shared__ float Bs[16][65];          // [kk][ll] heads^T (padded)
  float acc[4][4] = {};
  for(int d0=0; d0<ND; d0+=16){
    __syncthreads();
    {
      int f = tid << 2;
      int kk = f >> 6, ee = f & 63;
      const float* wp = Wo + (d0+kk)*ND + e0 + ee;
      #pragma unroll
      for(int j=0;j<4;j++) As[kk][ee+j] = wp[j];
    }
    {
      int f = tid << 2;
      int ll = f >> 4, kk = f & 15;
      const float* hp = heads + (b*NL + l0 + ll)*ND + d0 + kk;
      #pragma unroll
      for(int j=0;j<4;j++) Bs[kk+j][ll] = hp[j];
    }
    __syncthreads();
    #pragma unroll
    for(int kk=0;kk<16;kk++){
      float a[4], c[4];
      #pragma unroll
      for(int i=0;i<4;i++) a[i] = As[kk][ty + 16*i];
      #pragma unroll
      for(int j=0;j<4;j++) c[j] = Bs[kk][tx + 16*j];
      #pragma unroll
      for(int i=0;i<4;i++)
        #pragma unroll
        for(int j=0;j<4;j++) acc[i][j] += a[i]*c[j];
    }
  }
  float s=0.f, ss=0.f;
  #pragma unroll
  for(int i=0;i<4;i++){
    int e = e0 + ty + 16*i;
    int base = ((b*ND + e) << 10) + l0 + tx;
    #pragma unroll
    for(int j=0;j<4;j++){
      float r = R[base + 16*j] + acc[i][j];
      R[base + 16*j] = r;
      s += r; ss += r*r;
    }
  }
  stats_reduce(s, ss, stats, 5, b);
}

// ---------------- FC: out = relu(fc_w * LN5(R) + fc_b) + R -> d_out ----------------
__global__ __launch_bounds__(256) void k_fc(const float* __restrict__ R, const float* __restrict__ g,
                                            const float* __restrict__ bt, const float* __restrict__ stats,
                                            const float* __restrict__ W, const float* __restrict__ bias,
                                            float* __restrict__ out){
  int blk = blockIdx.x;
  int l0 = (blk & 15) << 6;
  int e0 = ((blk >> 4) & 3) << 6;
  int b  = blk >> 6;
  int tid = threadIdx.x;
  int tx = tid & 15, ty = tid >> 4;     // tx->l, ty->e
  float mean, rstd; ln_ab(stats, 5, b, mean, rstd);
  __shared__ float As[16][65];          // [kk][ee] fc_w (padded)
  __shared__ float Bs[16][64];          // [kk][ll] normalized input
  float acc[4][4] = {};
  for(int d0=0; d0<ND; d0+=16){
    __syncthreads();
    {
      int f = tid << 2;
      int ee = f >> 4, kk = f & 15;
      const float* wp = W + (e0+ee)*ND + d0 + kk;
      #pragma unroll
      for(int j=0;j<4;j++) As[kk+j][ee] = wp[j];
    }
    {
      int f = tid << 2;
      int kk = f >> 6, ll = f & 63;
      int gbase = ((d0+kk) << 10) + l0 + ll;
      const float* ip = R + (b << 18) + gbase;
      #pragma unroll
      for(int j=0;j<4;j++) Bs[kk][ll+j] = (ip[j] - mean)*rstd*g[gbase+j] + bt[gbase+j];
    }
    __syncthreads();
    #pragma unroll
    for(int kk=0;kk<16;kk++){
      float a[4], c[4];
      #pragma unroll
      for(int i=0;i<4;i++) a[i] = As[kk][ty + 16*i];
      #pragma unroll
      for(int j=0;j<4;j++) c[j] = Bs[kk][tx + 16*j];
      #pragma unroll
      for(int i=0;i<4;i++)
        #pragma unroll
        for(int j=0;j<4;j++) acc[i][j] += a[i]*c[j];
    }
  }
  #pragma unroll
  for(int i=0;i<4;i++){
    int e = e0 + ty + 16*i;
    float bv = bias[e];
    int base = ((b*ND + e) << 10) + l0 + tx;
    #pragma unroll
    for(int j=0;j<4;j++){
      float v = fmaxf(acc[i][j] + bv, 0.f);
      out[base + 16*j] = v + R[base + 16*j];
    }
  }
}

extern "C" void kernel_launch(void* const* d_in, const int* in_sizes, int n_in,
                              void* d_out, int out_size, void* d_ws, size_t ws_size,
                              hipStream_t stream){
  const float* x    = (const float*)d_in[0];
  const int*   mask = (const int*)d_in[1];
  const float* dw_w = (const float*)d_in[2];
  const float* dw_b = (const float*)d_in[3];
  const float* pw_w = (const float*)d_in[4];
  const float* pw_b = (const float*)d_in[5];
  const float* ln_g = (const float*)d_in[6];
  const float* ln_b = (const float*)d_in[7];
  const float* Wq   = (const float*)d_in[8];
  const float* Wk   = (const float*)d_in[9];
  const float* Wv   = (const float*)d_in[10];
  const float* Wo   = (const float*)d_in[11];
  const float* fc_w = (const float*)d_in[12];
  const float* fc_b = (const float*)d_in[13];

  float* ws    = (float*)d_ws;
  float* pos   = ws;                    // 262144 floats
  float* stats = ws + 262144;           // 256 floats (6 slots x 16 x 2 used)
  float* R     = ws + 262400;           // 4 Mi floats
  float* TMP   = R   + 4194304;         // 4 Mi floats (dw out; later heads)
  float* Qb    = TMP + 4194304;
  float* Kbuf  = Qb  + 4194304;
  float* Vbuf  = Kbuf+ 4194304;

  hipMemsetAsync(stats, 0, 256*sizeof(float), stream);
  k_pos<<<1024,256,0,stream>>>(pos);
  k_posadd<<<16384,256,0,stream>>>(x, pos, R, stats);
  for(int i=0;i<NCONV;i++){
    k_dwconv<<<16384,256,0,stream>>>(R, ln_g + (size_t)i*NPB, ln_b + (size_t)i*NPB,
                                     dw_w + i*ND*NKW, dw_b + i*ND, stats, TMP, i);
    k_pw<<<1024,256,0,stream>>>(TMP, pw_w + i*ND*ND, pw_b + i*ND, R, stats, i+1);
  }
  k_qkv<<<1024,256,0,stream>>>(R, ln_g + (size_t)4*NPB, ln_b + (size_t)4*NPB, stats, Wq, Qb);
  k_qkv<<<1024,256,0,stream>>>(R, ln_g + (size_t)4*NPB, ln_b + (size_t)4*NPB, stats, Wk, Kbuf);
  k_qkv<<<1024,256,0,stream>>>(R, ln_g + (size_t)4*NPB, ln_b + (size_t)4*NPB, stats, Wv, Vbuf);
  k_attn<<<512,256,0,stream>>>(Qb, Kbuf, Vbuf, mask, TMP);
  k_wo<<<1024,256,0,stream>>>(TMP, Wo, R, stats);
  k_fc<<<1024,256,0,stream>>>(R, ln_g + (size_t)5*NPB, ln_b + (size_t)5*NPB, stats, fc_w, fc_b, (float*)d_out);
}

// Round 2
// 952.641 us; speedup vs baseline: 1.5792x; 1.5792x over previous
//
#include <hip/hip_runtime.h>
#include <hip/hip_bf16.h>

#define NB 16
#define ND 256
#define NL 1024
#define NHH 8
#define NDK 32
#define NKW 7
#define NCONV 4
#define NPB (ND*NL)   // 262144 elements per batch item for LN

constexpr float LN_EPS = 1e-5f;

typedef __attribute__((ext_vector_type(8))) short bf16x8;
typedef __attribute__((ext_vector_type(4))) short bf16x4;
typedef __attribute__((ext_vector_type(4))) float f32x4;

__device__ __forceinline__ short bf16s(float f){   // RNE f32->bf16
  unsigned u = __builtin_bit_cast(unsigned, f);
  u += 0x7fff + ((u >> 16) & 1);
  return (short)(u >> 16);
}

// ---------------- LN helpers ----------------
__device__ __forceinline__ void ln_ab(const float* st, int slot, int b, float& mean, float& rstd){
  float s  = st[(slot*NB + b)*2];
  float ss = st[(slot*NB + b)*2 + 1];
  mean = s * (1.0f/NPB);
  float var = ss * (1.0f/NPB) - mean*mean;
  rstd = rsqrtf(var + LN_EPS);
}

__device__ __forceinline__ void stats_reduce(float s, float ss, float* stats, int slot, int b){
  __shared__ float red[8];
  #pragma unroll
  for(int o=32;o>0;o>>=1){ s += __shfl_down(s,o); ss += __shfl_down(ss,o); }
  int lane = threadIdx.x & 63, w = threadIdx.x >> 6;
  if(lane==0){ red[w*2]=s; red[w*2+1]=ss; }
  __syncthreads();
  if(threadIdx.x==0){
    atomicAdd(&stats[(slot*NB+b)*2],   red[0]+red[2]+red[4]+red[6]);
    atomicAdd(&stats[(slot*NB+b)*2+1], red[1]+red[3]+red[5]+red[7]);
  }
}

// ---------------- positional encoding table (D x L) ----------------
__global__ __launch_bounds__(256) void k_pos(float* __restrict__ pos){
  int idx = blockIdx.x*256 + threadIdx.x;
  int d = idx >> 10, l = idx & (NL-1);
  float fd = (float)d;
  const float LN1E4_OVER_D = 9.210340371976184f / (float)ND;
  float freq, phase;
  if((d & 1) == 0){ freq =  __expf(-fd*LN1E4_OVER_D);      phase = 0.f; }
  else            { freq = -__expf((1.f-fd)*LN1E4_OVER_D); phase = 1.5707963267948966f; }
  pos[idx] = sinf((float)l * freq + phase);
}

// ---------------- x + pos, accumulate LN0 stats ----------------
__global__ __launch_bounds__(256) void k_posadd(const float* __restrict__ x, const float* __restrict__ pos,
                                                float* __restrict__ R, float* __restrict__ stats){
  int idx = blockIdx.x*256 + threadIdx.x;
  int b = idx >> 18;            // D*L = 2^18
  int dl = idx & (NPB-1);
  float v = x[idx] + pos[dl];
  R[idx] = v;
  stats_reduce(v, v*v, stats, 0, b);
}

// ---------------- depthwise conv (LN applied on the fly) ----------------
__global__ __launch_bounds__(256) void k_dwconv(const float* __restrict__ R, const float* __restrict__ g,
                                                const float* __restrict__ bt, const float* __restrict__ w7,
                                                const float* __restrict__ b1, const float* __restrict__ stats,
                                                float* __restrict__ out, int slot){
  int blk = blockIdx.x;
  int l0 = (blk & 3) << 8;           // L/256 = 4 segments
  int d  = (blk >> 2) & (ND-1);
  int b  = blk >> 10;
  float mean, rstd; ln_ab(stats, slot, b, mean, rstd);
  __shared__ float tile[256 + NKW - 1];
  int rowoff = ((b*ND + d) << 10);
  int goff   = d << 10;
  for(int j = threadIdx.x; j < 256 + NKW - 1; j += 256){
    int l = l0 - (NKW/2) + j;
    float v = 0.f;
    if(l >= 0 && l < NL){
      v = (R[rowoff + l] - mean) * rstd * g[goff + l] + bt[goff + l];
    }
    tile[j] = v;
  }
  __syncthreads();
  float acc = b1[d];
  #pragma unroll
  for(int q=0;q<NKW;q++) acc += tile[threadIdx.x + q] * w7[d*NKW + q];
  out[rowoff + l0 + threadIdx.x] = acc;
}

// ---------------- pointwise conv GEMM: R = relu(W*In + bias) + R, stats ----------------
__global__ __launch_bounds__(256) void k_pw(const float* __restrict__ In, const float* __restrict__ W,
                                            const float* __restrict__ bias, float* __restrict__ R,
                                            float* __restrict__ stats, int slot_out){
  int blk = blockIdx.x;
  int l0 = (blk & 15) << 6;
  int e0 = ((blk >> 4) & 3) << 6;
  int b  = blk >> 6;
  int tid = threadIdx.x;
  int tx = tid & 15, ty = tid >> 4;     // tx->l, ty->e
  __shared__ float As[16][65];          // [kk][ee] weights (padded)
  __shared__ float Bs[16][64];          // [kk][ll] input
  float acc[4][4] = {};
  for(int d0=0; d0<ND; d0+=16){
    __syncthreads();
    {
      int f = tid << 2;
      int ee = f >> 4, kk = f & 15;
      const float* wp = W + (e0+ee)*ND + d0 + kk;
      #pragma unroll
      for(int j=0;j<4;j++) As[kk+j][ee] = wp[j];
    }
    {
      int f = tid << 2;
      int kk = f >> 6, ll = f & 63;
      const float* ip = In + ((b*ND + d0 + kk) << 10) + l0 + ll;
      #pragma unroll
      for(int j=0;j<4;j++) Bs[kk][ll+j] = ip[j];
    }
    __syncthreads();
    #pragma unroll
    for(int kk=0;kk<16;kk++){
      float a[4], c[4];
      #pragma unroll
      for(int i=0;i<4;i++) a[i] = As[kk][ty + 16*i];
      #pragma unroll
      for(int j=0;j<4;j++) c[j] = Bs[kk][tx + 16*j];
      #pragma unroll
      for(int i=0;i<4;i++)
        #pragma unroll
        for(int j=0;j<4;j++) acc[i][j] += a[i]*c[j];
    }
  }
  float s=0.f, ss=0.f;
  #pragma unroll
  for(int i=0;i<4;i++){
    int e = e0 + ty + 16*i;
    float bv = bias[e];
    int base = ((b*ND + e) << 10) + l0 + tx;
    #pragma unroll
    for(int j=0;j<4;j++){
      float v = fmaxf(acc[i][j] + bv, 0.f);
      float r = R[base + 16*j] + v;
      R[base + 16*j] = r;
      s += r; ss += r*r;
    }
  }
  stats_reduce(s, ss, stats, slot_out, b);
}

// ---------------- Q/K projection GEMM (LN4 fused): bf16 out[b][h][l][dk] ----------------
__global__ __launch_bounds__(256) void k_qkv(const float* __restrict__ R, const float* __restrict__ g,
                                             const float* __restrict__ bt, const float* __restrict__ stats,
                                             const float* __restrict__ Wh, short* __restrict__ out){
  int blk = blockIdx.x;
  int l0 = (blk & 15) << 6;
  int o0 = ((blk >> 4) & 3) << 6;
  int b  = blk >> 6;
  int tid = threadIdx.x;
  int tx = tid & 15, ty = tid >> 4;     // tx->o, ty->l
  float mean, rstd; ln_ab(stats, 4, b, mean, rstd);
  __shared__ float As[16][64];          // [kk][ll] normalized input
  __shared__ float Bs[16][64];          // [kk][oo] weight
  float acc[4][4] = {};
  for(int d0=0; d0<ND; d0+=16){
    __syncthreads();
    {
      int f = tid << 2;
      int kk = f >> 6, ll = f & 63;
      int gbase = ((d0+kk) << 10) + l0 + ll;
      const float* ip = R + (b << 18) + gbase;
      #pragma unroll
      for(int j=0;j<4;j++) As[kk][ll+j] = (ip[j] - mean)*rstd*g[gbase+j] + bt[gbase+j];
    }
    {
      int f = tid << 2;
      int kk = f >> 6, oo = f & 63;
      int o = o0 + oo;
      int h = o >> 5, k = o & 31;
      const float* wp = Wh + (h*ND + d0 + kk)*NDK + k;
      #pragma unroll
      for(int j=0;j<4;j++) Bs[kk][oo+j] = wp[j];
    }
    __syncthreads();
    #pragma unroll
    for(int kk=0;kk<16;kk++){
      float a[4], c[4];
      #pragma unroll
      for(int i=0;i<4;i++) a[i] = As[kk][ty + 16*i];
      #pragma unroll
      for(int j=0;j<4;j++) c[j] = Bs[kk][tx + 16*j];
      #pragma unroll
      for(int i=0;i<4;i++)
        #pragma unroll
        for(int j=0;j<4;j++) acc[i][j] += a[i]*c[j];
    }
  }
  #pragma unroll
  for(int i=0;i<4;i++){
    int l = l0 + ty + 16*i;
    #pragma unroll
    for(int j=0;j<4;j++){
      int o = o0 + tx + 16*j;
      int h = o >> 5, dk = o & 31;
      out[((size_t)(b*NHH + h)*NL + l)*NDK + dk] = bf16s(acc[i][j]);
    }
  }
}

// ---------------- V projection (LN4 fused): bf16 V^T out[b][h][v][l] ----------------
__global__ __launch_bounds__(256) void k_v(const float* __restrict__ R, const float* __restrict__ g,
                                           const float* __restrict__ bt, const float* __restrict__ stats,
                                           const float* __restrict__ Wv, short* __restrict__ out){
  int blk = blockIdx.x;
  int l0 = (blk & 15) << 6;
  int o0 = ((blk >> 4) & 3) << 6;
  int b  = blk >> 6;
  int tid = threadIdx.x;
  int tx = tid & 15, ty = tid >> 4;     // tx->l, ty->o
  float mean, rstd; ln_ab(stats, 4, b, mean, rstd);
  __shared__ float As[16][65];          // [kk][oo] weight (padded)
  __shared__ float Bs[16][64];          // [kk][ll] normalized input
  float acc[4][4] = {};
  for(int d0=0; d0<ND; d0+=16){
    __syncthreads();
    {
      int f = tid << 2;
      int ee = f >> 4, kk = f & 15;
      int o = o0 + ee; int hh = o >> 5, v = o & 31;
      #pragma unroll
      for(int j=0;j<4;j++) As[kk+j][ee] = Wv[((size_t)hh*ND + d0 + kk + j)*NDK + v];
    }
    {
      int f = tid << 2;
      int kk = f >> 6, ll = f & 63;
      int gbase = ((d0+kk) << 10) + l0 + ll;
      const float* ip = R + (b << 18) + gbase;
      #pragma unroll
      for(int j=0;j<4;j++) Bs[kk][ll+j] = (ip[j] - mean)*rstd*g[gbase+j] + bt[gbase+j];
    }
    __syncthreads();
    #pragma unroll
    for(int kk=0;kk<16;kk++){
      float a[4], c[4];
      #pragma unroll
      for(int i=0;i<4;i++) a[i] = As[kk][ty + 16*i];
      #pragma unroll
      for(int j=0;j<4;j++) c[j] = Bs[kk][tx + 16*j];
      #pragma unroll
      for(int i=0;i<4;i++)
        #pragma unroll
        for(int j=0;j<4;j++) acc[i][j] += a[i]*c[j];
    }
  }
  #pragma unroll
  for(int i=0;i<4;i++){
    int o = o0 + ty + 16*i;
    int hh = o >> 5, v = o & 31;
    #pragma unroll
    for(int j=0;j<4;j++){
      int l = l0 + tx + 16*j;
      out[((size_t)(b*NHH + hh)*NDK + v)*NL + l] = bf16s(acc[i][j]);
    }
  }
}

// ---------------- MFMA flash attention ----------------
// wg = (b, h, 64-query block), 4 waves x 16 queries.
// S^T = mfma(K_frag, Q_frag): C col=query(lane&15), row=key((lane>>4)*4+r)
// PV  = mfma(P_frag, V^T_frag): C col=v, row=query
__global__ __launch_bounds__(256) void k_attn(const short* __restrict__ Qb, const short* __restrict__ Kb,
                                              const short* __restrict__ Vt, const int* __restrict__ mask,
                                              float* __restrict__ heads){
  int blk = blockIdx.x;
  int qblk = blk & 15, h = (blk >> 4) & 7, b = blk >> 7;
  int bh = b*NHH + h;
  int tid = threadIdx.x;
  int w = tid >> 6, lane = tid & 63;
  int lq = lane & 15, gg = lane >> 4;

  __shared__ short Ks[64][40];     // K tile, padded (2-way bank alias = free)
  __shared__ short Vs[32][72];     // V^T tile, padded
  __shared__ short Ps[4][16][40];  // per-wave P scratch
  __shared__ float msh[64];

  // Q fragment (B operand of S^T): lane holds col q=lq, k(dk) = gg*8..+7
  int qrow = qblk*64 + w*16 + lq;
  bf16x8 qf = *(const bf16x8*)(Qb + ((size_t)bh*NL + qrow)*NDK + gg*8);

  f32x4 zero = {0.f,0.f,0.f,0.f};
  f32x4 o0 = zero, o1 = zero;
  float dacc = 0.f;
  const float scale = 0.17677669529663687f;   // 1/sqrt(32)

  for(int t0=0; t0<NL; t0+=64){
    __syncthreads();
    {
      int key = tid >> 2, c = tid & 3;
      *(bf16x8*)(&Ks[key][c*8]) = *(const bf16x8*)(Kb + ((size_t)bh*NL + t0 + key)*NDK + c*8);
      int v = tid >> 3, ch = tid & 7;
      *(bf16x8*)(&Vs[v][ch*8]) = *(const bf16x8*)(Vt + ((size_t)bh*NDK + v)*NL + t0 + ch*8);
      if(tid < 64) msh[tid] = (float)mask[b*NL + t0 + tid];
    }
    __syncthreads();
    #pragma unroll
    for(int sub=0; sub<2; sub++){
      bf16x8 a0 = *(const bf16x8*)(&Ks[sub*32 + lq][gg*8]);
      bf16x8 a1 = *(const bf16x8*)(&Ks[sub*32 + 16 + lq][gg*8]);
      f32x4 c0 = __builtin_amdgcn_mfma_f32_16x16x32_bf16(a0, qf, zero, 0, 0, 0);
      f32x4 c1 = __builtin_amdgcn_mfma_f32_16x16x32_bf16(a1, qf, zero, 0, 0, 0);
      bf16x4 p0, p1;
      #pragma unroll
      for(int r=0;r<4;r++){
        float mv0 = msh[sub*32 + gg*4 + r];
        float pv0 = mv0 * __expf(c0[r]*scale);     // masked->0 exactly; scores O(1)
        dacc += pv0;
        p0[r] = bf16s(pv0);
        float mv1 = msh[sub*32 + 16 + gg*4 + r];
        float pv1 = mv1 * __expf(c1[r]*scale);
        dacc += pv1;
        p1[r] = bf16s(pv1);
      }
      // P layout in LDS: [q][32 keys of this sub-tile] (same-wave producer/consumer)
      *(bf16x4*)(&Ps[w][lq][gg*4])      = p0;
      *(bf16x4*)(&Ps[w][lq][16 + gg*4]) = p1;
      bf16x8 pf = *(const bf16x8*)(&Ps[w][lq][gg*8]);
      bf16x8 b0 = *(const bf16x8*)(&Vs[lq][sub*32 + gg*8]);
      bf16x8 b1 = *(const bf16x8*)(&Vs[16 + lq][sub*32 + gg*8]);
      o0 = __builtin_amdgcn_mfma_f32_16x16x32_bf16(pf, b0, o0, 0, 0, 0);
      o1 = __builtin_amdgcn_mfma_f32_16x16x32_bf16(pf, b1, o1, 0, 0, 0);
    }
  }
  // denom: lane holds partial for query lq over its gg key-subset -> reduce over gg groups
  dacc += __shfl_xor(dacc, 16);
  dacc += __shfl_xor(dacc, 32);
  #pragma unroll
  for(int r=0;r<4;r++){
    int ql = gg*4 + r;                       // wave-local output row
    float dn = __shfl(dacc, ql);             // lane ql holds denom for query ql
    int qg = qblk*64 + w*16 + ql;
    float mq = (float)mask[b*NL + qg];
    float sc = mq / dn;
    float* op = heads + ((size_t)(b*NL + qg))*(NHH*NDK) + h*NDK;
    op[lq]      = o0[r]*sc;
    op[16 + lq] = o1[r]*sc;
  }
}

// ---------------- output projection: R += heads @ Wo, stats slot 5 ----------------
__global__ __launch_bounds__(256) void k_wo(const float* __restrict__ heads, const float* __restrict__ Wo,
                                            float* __restrict__ R, float* __restrict__ stats){
  int blk = blockIdx.x;
  int l0 = (blk & 15) << 6;
  int e0 = ((blk >> 4) & 3) << 6;
  int b  = blk >> 6;
  int tid = threadIdx.x;
  int tx = tid & 15, ty = tid >> 4;     // tx->l, ty->e
  __shared__ float As[16][64];          // [kk][ee] Wo
  __shared__ float Bs[16][65];          // [kk][ll] heads^T (padded)
  float acc[4][4] = {};
  for(int d0=0; d0<ND; d0+=16){
    __syncthreads();
    {
      int f = tid << 2;
      int kk = f >> 6, ee = f & 63;
      const float* wp = Wo + (d0+kk)*ND + e0 + ee;
      #pragma unroll
      for(int j=0;j<4;j++) As[kk][ee+j] = wp[j];
    }
    {
      int f = tid << 2;
      int ll = f >> 4, kk = f & 15;
      const float* hp = heads + (b*NL + l0 + ll)*ND + d0 + kk;
      #pragma unroll
      for(int j=0;j<4;j++) Bs[kk+j][ll] = hp[j];
    }
    __syncthreads();
    #pragma unroll
    for(int kk=0;kk<16;kk++){
      float a[4], c[4];
      #pragma unroll
      for(int i=0;i<4;i++) a[i] = As[kk][ty + 16*i];
      #pragma unroll
      for(int j=0;j<4;j++) c[j] = Bs[kk][tx + 16*j];
      #pragma unroll
      for(int i=0;i<4;i++)
        #pragma unroll
        for(int j=0;j<4;j++) acc[i][j] += a[i]*c[j];
    }
  }
  float s=0.f, ss=0.f;
  #pragma unroll
  for(int i=0;i<4;i++){
    int e = e0 + ty + 16*i;
    int base = ((b*ND + e) << 10) + l0 + tx;
    #pragma unroll
    for(int j=0;j<4;j++){
      float r = R[base + 16*j] + acc[i][j];
      R[base + 16*j] = r;
      s += r; ss += r*r;
    }
  }
  stats_reduce(s, ss, stats, 5, b);
}

// ---------------- FC: out = relu(fc_w * LN5(R) + fc_b) + R -> d_out ----------------
__global__ __launch_bounds__(256) void k_fc(const float* __restrict__ R, const float* __restrict__ g,
                                            const float* __restrict__ bt, const float* __restrict__ stats,
                                            const float* __restrict__ W, const float* __restrict__ bias,
                                            float* __restrict__ out){
  int blk = blockIdx.x;
  int l0 = (blk & 15) << 6;
  int e0 = ((blk >> 4) & 3) << 6;
  int b  = blk >> 6;
  int tid = threadIdx.x;
  int tx = tid & 15, ty = tid >> 4;     // tx->l, ty->e
  float mean, rstd; ln_ab(stats, 5, b, mean, rstd);
  __shared__ float As[16][65];          // [kk][ee] fc_w (padded)
  __shared__ float Bs[16][64];          // [kk][ll] normalized input
  float acc[4][4] = {};
  for(int d0=0; d0<ND; d0+=16){
    __syncthreads();
    {
      int f = tid << 2;
      int ee = f >> 4, kk = f & 15;
      const float* wp = W + (e0+ee)*ND + d0 + kk;
      #pragma unroll
      for(int j=0;j<4;j++) As[kk+j][ee] = wp[j];
    }
    {
      int f = tid << 2;
      int kk = f >> 6, ll = f & 63;
      int gbase = ((d0+kk) << 10) + l0 + ll;
      const float* ip = R + (b << 18) + gbase;
      #pragma unroll
      for(int j=0;j<4;j++) Bs[kk][ll+j] = (ip[j] - mean)*rstd*g[gbase+j] + bt[gbase+j];
    }
    __syncthreads();
    #pragma unroll
    for(int kk=0;kk<16;kk++){
      float a[4], c[4];
      #pragma unroll
      for(int i=0;i<4;i++) a[i] = As[kk][ty + 16*i];
      #pragma unroll
      for(int j=0;j<4;j++) c[j] = Bs[kk][tx + 16*j];
      #pragma unroll
      for(int i=0;i<4;i++)
        #pragma unroll
        for(int j=0;j<4;j++) acc[i][j] += a[i]*c[j];
    }
  }
  #pragma unroll
  for(int i=0;i<4;i++){
    int e = e0 + ty + 16*i;
    float bv = bias[e];
    int base = ((b*ND + e) << 10) + l0 + tx;
    #pragma unroll
    for(int j=0;j<4;j++){
      float v = fmaxf(acc[i][j] + bv, 0.f);
      out[base + 16*j] = v + R[base + 16*j];
    }
  }
}

extern "C" void kernel_launch(void* const* d_in, const int* in_sizes, int n_in,
                              void* d_out, int out_size, void* d_ws, size_t ws_size,
                              hipStream_t stream){
  const float* x    = (const float*)d_in[0];
  const int*   mask = (const int*)d_in[1];
  const float* dw_w = (const float*)d_in[2];
  const float* dw_b = (const float*)d_in[3];
  const float* pw_w = (const float*)d_in[4];
  const float* pw_b = (const float*)d_in[5];
  const float* ln_g = (const float*)d_in[6];
  const float* ln_b = (const float*)d_in[7];
  const float* Wq   = (const float*)d_in[8];
  const float* Wk   = (const float*)d_in[9];
  const float* Wv   = (const float*)d_in[10];
  const float* Wo   = (const float*)d_in[11];
  const float* fc_w = (const float*)d_in[12];
  const float* fc_b = (const float*)d_in[13];

  float* ws    = (float*)d_ws;
  float* pos   = ws;                    // 262144 floats
  float* stats = ws + 262144;           // 256 floats
  float* R     = ws + 262400;           // 4 Mi floats
  float* TMP   = R   + 4194304;         // 4 Mi floats (dw out; later heads fp32)
  short* Qb    = (short*)(TMP + 4194304);       // 4 Mi bf16
  short* Kbuf  = Qb  + 4194304;
  short* Vbuf  = Kbuf + 4194304;

  hipMemsetAsync(stats, 0, 256*sizeof(float), stream);
  k_pos<<<1024,256,0,stream>>>(pos);
  k_posadd<<<16384,256,0,stream>>>(x, pos, R, stats);
  for(int i=0;i<NCONV;i++){
    k_dwconv<<<16384,256,0,stream>>>(R, ln_g + (size_t)i*NPB, ln_b + (size_t)i*NPB,
                                     dw_w + i*ND*NKW, dw_b + i*ND, stats, TMP, i);
    k_pw<<<1024,256,0,stream>>>(TMP, pw_w + i*ND*ND, pw_b + i*ND, R, stats, i+1);
  }
  k_qkv<<<1024,256,0,stream>>>(R, ln_g + (size_t)4*NPB, ln_b + (size_t)4*NPB, stats, Wq, Qb);
  k_qkv<<<1024,256,0,stream>>>(R, ln_g + (size_t)4*NPB, ln_b + (size_t)4*NPB, stats, Wk, Kbuf);
  k_v  <<<1024,256,0,stream>>>(R, ln_g + (size_t)4*NPB, ln_b + (size_t)4*NPB, stats, Wv, Vbuf);
  k_attn<<<2048,256,0,stream>>>(Qb, Kbuf, Vbuf, mask, TMP);
  k_wo<<<1024,256,0,stream>>>(TMP, Wo, R, stats);
  k_fc<<<1024,256,0,stream>>>(R, ln_g + (size_t)5*NPB, ln_b + (size_t)5*NPB, stats, fc_w, fc_b, (float*)d_out);
}

// Round 3
// 471.062 us; speedup vs baseline: 3.1936x; 2.0223x over previous
//
#include <hip/hip_runtime.h>
#include <hip/hip_bf16.h>

#define NB 16
#define ND 256
#define NL 1024
#define NHH 8
#define NDK 32
#define NKW 7
#define NCONV 4
#define NPB (ND*NL)

constexpr float LN_EPS = 1e-5f;

typedef __attribute__((ext_vector_type(4))) float f32x4;
typedef __attribute__((ext_vector_type(4))) short bf16x4;
typedef __attribute__((ext_vector_type(8))) short bf16x8;

__device__ __forceinline__ short bf16s(float f){   // RNE f32->bf16
  unsigned u = __builtin_bit_cast(unsigned, f);
  u += 0x7fff + ((u >> 16) & 1);
  return (short)(u >> 16);
}
__device__ __forceinline__ float b2f(short s){
  return __builtin_bit_cast(float, ((unsigned)(unsigned short)s) << 16);
}

// ---------------- LN stats: 8 bins x 128B apart per (slot,b) ----------------
// stats[((slot*16+b)*8+bin)*32 + {0,1}]
__device__ __forceinline__ void ln_ab(const float* st, int slot, int b, float& mean, float& rstd){
  float s = 0.f, ss = 0.f;
  #pragma unroll
  for(int bin=0;bin<8;bin++){
    const float* p = st + ((size_t)((slot*NB+b)*8+bin))*32;
    s += p[0]; ss += p[1];
  }
  mean = s * (1.0f/NPB);
  float var = ss * (1.0f/NPB) - mean*mean;
  rstd = rsqrtf(var + LN_EPS);
}

__device__ __forceinline__ void stats_reduce(float s, float ss, float* stats, int slot, int b, int bin){
  __shared__ float red[8];
  #pragma unroll
  for(int o=32;o>0;o>>=1){ s += __shfl_down(s,o); ss += __shfl_down(ss,o); }
  int lane = threadIdx.x & 63, w = threadIdx.x >> 6;
  if(lane==0){ red[w*2]=s; red[w*2+1]=ss; }
  __syncthreads();
  if(threadIdx.x==0){
    float* p = stats + ((size_t)((slot*NB+b)*8+bin))*32;
    atomicAdd(&p[0], red[0]+red[2]+red[4]+red[6]);
    atomicAdd(&p[1], red[1]+red[3]+red[5]+red[7]);
  }
}

// ---------------- weight prep kernels ----------------
__global__ __launch_bounds__(256) void k_wcvt(const float* __restrict__ in, short* __restrict__ out){
  int idx = blockIdx.x*256 + threadIdx.x;
  f32x4 v = *(const f32x4*)(in + idx*4);
  bf16x4 o;
  #pragma unroll
  for(int j=0;j<4;j++) o[j] = bf16s(v[j]);
  *(bf16x4*)(out + idx*4) = o;
}
// Wo[d][e] -> bf16 [e][d]
__global__ __launch_bounds__(256) void k_wtr(const float* __restrict__ Wo, short* __restrict__ out){
  int idx = blockIdx.x*256 + threadIdx.x;
  int e = idx >> 8, d = idx & 255;
  out[idx] = bf16s(Wo[d*ND + e]);
}
// W[h][d][k] -> bf16 [(h*32+k)][d]
__global__ __launch_bounds__(256) void k_wqkv(const float* __restrict__ W, short* __restrict__ out){
  int idx = blockIdx.x*256 + threadIdx.x;
  int o = idx >> 8, d = idx & 255;
  int h = o >> 5, k = o & 31;
  out[idx] = bf16s(W[(h*ND + d)*NDK + k]);
}

// ---------------- transpose ln_g/ln_b [slot][d][l] -> bf16 [slot][l][d] ----------------
__global__ __launch_bounds__(256) void k_gbt(const float* __restrict__ g, const float* __restrict__ btab,
                                             short* __restrict__ gT, short* __restrict__ bT){
  int blk = blockIdx.x;
  int which = blk >> 6;          // 0..11
  int tile = blk & 63;
  int d0 = (tile & 3) << 6, l0 = (tile >> 2) << 6;
  const float* src = (which < 6) ? (g + (size_t)which*NPB) : (btab + (size_t)(which-6)*NPB);
  short* dst = (which < 6) ? (gT + (size_t)which*NPB) : (bT + (size_t)(which-6)*NPB);
  __shared__ float T[64][65];
  int tid = threadIdx.x;
  for(int i=tid;i<1024;i+=256){
    int dd = i>>4, l4 = i&15;
    f32x4 v = *(const f32x4*)(src + (size_t)(d0+dd)*NL + l0 + l4*4);
    #pragma unroll
    for(int j=0;j<4;j++) T[dd][l4*4+j] = v[j];
  }
  __syncthreads();
  for(int i=tid;i<1024;i+=256){
    int ll = i>>4, d4 = i&15;
    bf16x4 o;
    #pragma unroll
    for(int j=0;j<4;j++) o[j] = bf16s(T[d4*4+j][ll]);
    *(bf16x4*)(dst + (size_t)(l0+ll)*ND + d0 + d4*4) = o;
  }
}

// ---------------- x + pos -> R_T [b][l][d] fp32, stats slot 0 ----------------
__global__ __launch_bounds__(256) void k_posaddT(const float* __restrict__ x, float* __restrict__ R,
                                                 float* __restrict__ stats){
  int blk = blockIdx.x;
  int lt = blk & 15, dt = (blk>>4)&3, b = blk>>6;
  int l0 = lt*64, d0 = dt*64;
  __shared__ float T[64][65];
  int tid = threadIdx.x;
  float s=0.f, ss=0.f;
  const float LN1E4_OVER_D = 9.210340371976184f / (float)ND;
  for(int i=tid;i<1024;i+=256){
    int dd = i>>4, l4 = i&15;
    int d = d0+dd;
    float freq, phase;
    if((d & 1) == 0){ freq =  __expf(-(float)d*LN1E4_OVER_D);      phase = 0.f; }
    else            { freq = -__expf((1.f-(float)d)*LN1E4_OVER_D); phase = 1.5707963267948966f; }
    f32x4 xv = *(const f32x4*)(x + ((size_t)(b*ND+d)*NL) + l0 + l4*4);
    #pragma unroll
    for(int j=0;j<4;j++){
      float l = (float)(l0 + l4*4 + j);
      float v = xv[j] + sinf(l*freq + phase);
      T[dd][l4*4+j] = v;
      s += v; ss += v*v;
    }
  }
  __syncthreads();
  for(int i=tid;i<1024;i+=256){
    int ll = i>>4, d4 = i&15;
    f32x4 o;
    #pragma unroll
    for(int j=0;j<4;j++) o[j] = T[d4*4+j][ll];
    *(f32x4*)(R + ((size_t)(b*NL+l0+ll)*ND) + d0 + d4*4) = o;
  }
  stats_reduce(s, ss, stats, 0, b, blk & 7);
}

// ---------------- depthwise conv, transposed space, LN fused ----------------
// out Yb[b][l][d] (bf16) = sum_q LN(R[b][l+q-3][d]) * w7[d][q]  + db[d]
__global__ __launch_bounds__(256) void k_dwconvT(const float* __restrict__ R, const short* __restrict__ gT,
                                                 const short* __restrict__ bT, const float* __restrict__ w7,
                                                 const float* __restrict__ db, const float* __restrict__ stats,
                                                 short* __restrict__ Y, int slot){
  int idx = blockIdx.x*256 + threadIdx.x;
  int d = idx & 255, l = (idx>>8)&1023, b = idx>>18;
  float mean, rstd; ln_ab(stats, slot, b, mean, rstd);
  float acc = db[d];
  #pragma unroll
  for(int q=0;q<NKW;q++){
    int lp = l + q - 3;
    if(lp >= 0 && lp < NL){
      float v = R[((size_t)(b*NL+lp)*ND) + d];
      float nv = (v - mean)*rstd*b2f(gT[(size_t)lp*ND + d]) + b2f(bT[(size_t)lp*ND + d]);
      acc += nv * w7[d*NKW + q];
    }
  }
  Y[idx] = bf16s(acc);
}

// ---------------- shared MFMA GEMM pieces ----------------
// LDS tiles: [64 rows][128 k] bf16, row stride 256 bytes, XOR swizzle byte^=((row&7)<<4)
__device__ __forceinline__ void stage_rows_bf16(short* dst, const short* src, int tid, int c){
  for(int i=tid;i<1024;i+=256){
    int rr = i>>4, kk = i&15;
    bf16x8 w = *(const bf16x8*)(src + (size_t)rr*ND + c*128 + kk*8);
    *(bf16x8*)((char*)dst + rr*256 + ((kk*16) ^ ((rr&7)<<4))) = w;
  }
}
// activations fp32 with LN affine (g/b bf16), row stride ND floats
__device__ __forceinline__ void stage_act_ln(short* dst, const float* src, const short* g, const short* bt,
                                             float mean, float rstd, int tid, int c){
  for(int i=tid;i<2048;i+=256){
    int ll = i>>5, kk = i&31;
    size_t off = (size_t)ll*ND + c*128 + kk*4;
    f32x4 v = *(const f32x4*)(src + off);
    bf16x4 gv = *(const bf16x4*)(g + off);
    bf16x4 bv = *(const bf16x4*)(bt + off);
    bf16x4 o;
    #pragma unroll
    for(int j=0;j<4;j++) o[j] = bf16s((v[j]-mean)*rstd*b2f(gv[j]) + b2f(bv[j]));
    *(bf16x4*)((char*)dst + ll*256 + ((kk*8) ^ ((ll&7)<<4))) = o;
  }
}
__device__ __forceinline__ void mfma_core(const short* As, const short* Bs, int wm, int wn,
                                          int lq, int gg, f32x4 acc[2][2]){
  #pragma unroll
  for(int t=0;t<4;t++){
    bf16x8 a[2], bb[2];
    #pragma unroll
    for(int m=0;m<2;m++){
      int row = wm*32 + m*16 + lq;
      a[m] = *(const bf16x8*)((const char*)As + row*256 + ((t*64 + gg*16) ^ ((row&7)<<4)));
    }
    #pragma unroll
    for(int n=0;n<2;n++){
      int row = wn*32 + n*16 + lq;
      bb[n] = *(const bf16x8*)((const char*)Bs + row*256 + ((t*64 + gg*16) ^ ((row&7)<<4)));
    }
    #pragma unroll
    for(int m=0;m<2;m++)
      #pragma unroll
      for(int n=0;n<2;n++)
        acc[m][n] = __builtin_amdgcn_mfma_f32_16x16x32_bf16(a[m], bb[n], acc[m][n], 0,0,0);
  }
}

#define GEMM_PROLOGUE() \
  int blk = blockIdx.x; \
  int lt = blk & 15, et = (blk>>4)&3, b = blk>>6; \
  int l0 = lt*64, e0 = et*64; \
  int tid = threadIdx.x; \
  int w = tid>>6, lane = tid&63, lq = lane&15, gg = lane>>4; \
  int wm = w&1, wn = w>>1; \
  __shared__ short As[8192], Bs[8192]; \
  f32x4 acc[2][2]; \
  acc[0][0]=acc[0][1]=acc[1][0]=acc[1][1] = (f32x4){0.f,0.f,0.f,0.f};

// ---- pw: Yb(bf16) x W -> relu+bias, += R, stats ----
__global__ __launch_bounds__(256) void k_pw(const short* __restrict__ Y, const short* __restrict__ Wb,
                                            const float* __restrict__ bias, float* __restrict__ R,
                                            float* __restrict__ stats, int slot_out){
  GEMM_PROLOGUE();
  const short* Asrc = Y + ((size_t)(b*NL)+l0)*ND;
  const short* Bsrc = Wb + (size_t)e0*ND;
  for(int c=0;c<2;c++){
    __syncthreads();
    stage_rows_bf16(As, Asrc, tid, c);
    stage_rows_bf16(Bs, Bsrc, tid, c);
    __syncthreads();
    mfma_core(As, Bs, wm, wn, lq, gg, acc);
  }
  float s=0.f, ss=0.f;
  #pragma unroll
  for(int n=0;n<2;n++){
    int e = e0 + wn*32 + n*16 + lq;
    float bv = bias[e];
    #pragma unroll
    for(int m=0;m<2;m++){
      #pragma unroll
      for(int r=0;r<4;r++){
        int l = l0 + wm*32 + m*16 + gg*4 + r;
        size_t ix = (size_t)(b*NL+l)*ND + e;
        float v = fmaxf(acc[m][n][r] + bv, 0.f);
        float rr = R[ix] + v;
        R[ix] = rr;
        s += rr; ss += rr*rr;
      }
    }
  }
  stats_reduce(s, ss, stats, slot_out, b, blk & 7);
}

// ---- qk: LN(R) x W -> bf16 out[b][h][l][dk] ----
__global__ __launch_bounds__(256) void k_qk(const float* __restrict__ R, const short* __restrict__ gT,
                                            const short* __restrict__ bT, const float* __restrict__ stats,
                                            const short* __restrict__ Wb, short* __restrict__ out){
  GEMM_PROLOGUE();
  float mean, rstd; ln_ab(stats, 4, b, mean, rstd);
  const float* Asrc = R + ((size_t)(b*NL)+l0)*ND;
  const short* gs = gT + (size_t)l0*ND;
  const short* bs = bT + (size_t)l0*ND;
  const short* Bsrc = Wb + (size_t)e0*ND;
  for(int c=0;c<2;c++){
    __syncthreads();
    stage_act_ln(As, Asrc, gs, bs, mean, rstd, tid, c);
    stage_rows_bf16(Bs, Bsrc, tid, c);
    __syncthreads();
    mfma_core(As, Bs, wm, wn, lq, gg, acc);
  }
  #pragma unroll
  for(int n=0;n<2;n++){
    int o = e0 + wn*32 + n*16 + lq;
    int h = o>>5, dk = o&31;
    #pragma unroll
    for(int m=0;m<2;m++){
      #pragma unroll
      for(int r=0;r<4;r++){
        int l = l0 + wm*32 + m*16 + gg*4 + r;
        out[((size_t)(b*NHH+h)*NL + l)*NDK + dk] = bf16s(acc[m][n][r]);
      }
    }
  }
}

// ---- v: LN(R) x Wv -> bf16 V^T [b][h][v][l] ----
__global__ __launch_bounds__(256) void k_v(const float* __restrict__ R, const short* __restrict__ gT,
                                           const short* __restrict__ bT, const float* __restrict__ stats,
                                           const short* __restrict__ Wb, short* __restrict__ out){
  GEMM_PROLOGUE();
  float mean, rstd; ln_ab(stats, 4, b, mean, rstd);
  const float* Asrc = R + ((size_t)(b*NL)+l0)*ND;
  const short* gs = gT + (size_t)l0*ND;
  const short* bs = bT + (size_t)l0*ND;
  const short* Bsrc = Wb + (size_t)e0*ND;
  for(int c=0;c<2;c++){
    __syncthreads();
    stage_act_ln(As, Asrc, gs, bs, mean, rstd, tid, c);
    stage_rows_bf16(Bs, Bsrc, tid, c);
    __syncthreads();
    mfma_core(As, Bs, wm, wn, lq, gg, acc);
  }
  #pragma unroll
  for(int n=0;n<2;n++){
    int o = e0 + wn*32 + n*16 + lq;
    int h = o>>5, v = o&31;
    #pragma unroll
    for(int m=0;m<2;m++){
      int lb = l0 + wm*32 + m*16 + gg*4;
      bf16x4 pk;
      #pragma unroll
      for(int r=0;r<4;r++) pk[r] = bf16s(acc[m][n][r]);
      *(bf16x4*)(out + ((size_t)(b*NHH+h)*NDK + v)*NL + lb) = pk;
    }
  }
}

// ---- wo: heads(bf16) x Wo^T -> += R, stats slot 5 ----
__global__ __launch_bounds__(256) void k_wo(const short* __restrict__ H, const short* __restrict__ Wb,
                                            float* __restrict__ R, float* __restrict__ stats){
  GEMM_PROLOGUE();
  const short* Asrc = H + ((size_t)(b*NL)+l0)*ND;
  const short* Bsrc = Wb + (size_t)e0*ND;
  for(int c=0;c<2;c++){
    __syncthreads();
    stage_rows_bf16(As, Asrc, tid, c);
    stage_rows_bf16(Bs, Bsrc, tid, c);
    __syncthreads();
    mfma_core(As, Bs, wm, wn, lq, gg, acc);
  }
  float s=0.f, ss=0.f;
  #pragma unroll
  for(int n=0;n<2;n++){
    int e = e0 + wn*32 + n*16 + lq;
    #pragma unroll
    for(int m=0;m<2;m++){
      #pragma unroll
      for(int r=0;r<4;r++){
        int l = l0 + wm*32 + m*16 + gg*4 + r;
        size_t ix = (size_t)(b*NL+l)*ND + e;
        float rr = R[ix] + acc[m][n][r];
        R[ix] = rr;
        s += rr; ss += rr*rr;
      }
    }
  }
  stats_reduce(s, ss, stats, 5, b, blk & 7);
}

// ---- fc: LN5(R) x fc_w -> relu+bias, + R -> d_out [b][e][l] ----
__global__ __launch_bounds__(256) void k_fc(const float* __restrict__ R, const short* __restrict__ gT,
                                            const short* __restrict__ bT, const float* __restrict__ stats,
                                            const short* __restrict__ Wb, const float* __restrict__ bias,
                                            float* __restrict__ out){
  GEMM_PROLOGUE();
  float mean, rstd; ln_ab(stats, 5, b, mean, rstd);
  const float* Asrc = R + ((size_t)(b*NL)+l0)*ND;
  const short* gs = gT + (size_t)l0*ND;
  const short* bs = bT + (size_t)l0*ND;
  const short* Bsrc = Wb + (size_t)e0*ND;
  for(int c=0;c<2;c++){
    __syncthreads();
    stage_act_ln(As, Asrc, gs, bs, mean, rstd, tid, c);
    stage_rows_bf16(Bs, Bsrc, tid, c);
    __syncthreads();
    mfma_core(As, Bs, wm, wn, lq, gg, acc);
  }
  #pragma unroll
  for(int n=0;n<2;n++){
    int e = e0 + wn*32 + n*16 + lq;
    float bv = bias[e];
    #pragma unroll
    for(int m=0;m<2;m++){
      int lb = l0 + wm*32 + m*16 + gg*4;
      f32x4 ov;
      #pragma unroll
      for(int r=0;r<4;r++){
        float v = fmaxf(acc[m][n][r] + bv, 0.f);
        ov[r] = v + R[(size_t)(b*NL+lb+r)*ND + e];
      }
      *(f32x4*)(out + (size_t)(b*ND+e)*NL + lb) = ov;
    }
  }
}

// ---------------- MFMA flash attention (unchanged math; bf16 heads out) ----------------
__global__ __launch_bounds__(256) void k_attn(const short* __restrict__ Qb, const short* __restrict__ Kb,
                                              const short* __restrict__ Vt, const int* __restrict__ mask,
                                              short* __restrict__ heads){
  int blk = blockIdx.x;
  int qblk = blk & 15, h = (blk >> 4) & 7, b = blk >> 7;
  int bh = b*NHH + h;
  int tid = threadIdx.x;
  int w = tid >> 6, lane = tid & 63;
  int lq = lane & 15, gg = lane >> 4;

  __shared__ short Ks[64][40];
  __shared__ short Vs[32][72];
  __shared__ short Ps[4][16][40];
  __shared__ float msh[64];

  int qrow = qblk*64 + w*16 + lq;
  bf16x8 qf = *(const bf16x8*)(Qb + ((size_t)bh*NL + qrow)*NDK + gg*8);

  f32x4 zero = {0.f,0.f,0.f,0.f};
  f32x4 o0 = zero, o1 = zero;
  float dacc = 0.f;
  const float scale = 0.17677669529663687f;

  for(int t0=0; t0<NL; t0+=64){
    __syncthreads();
    {
      int key = tid >> 2, c = tid & 3;
      *(bf16x8*)(&Ks[key][c*8]) = *(const bf16x8*)(Kb + ((size_t)bh*NL + t0 + key)*NDK + c*8);
      int v = tid >> 3, ch = tid & 7;
      *(bf16x8*)(&Vs[v][ch*8]) = *(const bf16x8*)(Vt + ((size_t)bh*NDK + v)*NL + t0 + ch*8);
      if(tid < 64) msh[tid] = (float)mask[b*NL + t0 + tid];
    }
    __syncthreads();
    #pragma unroll
    for(int sub=0; sub<2; sub++){
      bf16x8 a0 = *(const bf16x8*)(&Ks[sub*32 + lq][gg*8]);
      bf16x8 a1 = *(const bf16x8*)(&Ks[sub*32 + 16 + lq][gg*8]);
      f32x4 c0 = __builtin_amdgcn_mfma_f32_16x16x32_bf16(a0, qf, zero, 0, 0, 0);
      f32x4 c1 = __builtin_amdgcn_mfma_f32_16x16x32_bf16(a1, qf, zero, 0, 0, 0);
      bf16x4 p0, p1;
      #pragma unroll
      for(int r=0;r<4;r++){
        float mv0 = msh[sub*32 + gg*4 + r];
        float pv0 = mv0 * __expf(c0[r]*scale);
        dacc += pv0;
        p0[r] = bf16s(pv0);
        float mv1 = msh[sub*32 + 16 + gg*4 + r];
        float pv1 = mv1 * __expf(c1[r]*scale);
        dacc += pv1;
        p1[r] = bf16s(pv1);
      }
      *(bf16x4*)(&Ps[w][lq][gg*4])      = p0;
      *(bf16x4*)(&Ps[w][lq][16 + gg*4]) = p1;
      bf16x8 pf = *(const bf16x8*)(&Ps[w][lq][gg*8]);
      bf16x8 b0 = *(const bf16x8*)(&Vs[lq][sub*32 + gg*8]);
      bf16x8 b1 = *(const bf16x8*)(&Vs[16 + lq][sub*32 + gg*8]);
      o0 = __builtin_amdgcn_mfma_f32_16x16x32_bf16(pf, b0, o0, 0, 0, 0);
      o1 = __builtin_amdgcn_mfma_f32_16x16x32_bf16(pf, b1, o1, 0, 0, 0);
    }
  }
  dacc += __shfl_xor(dacc, 16);
  dacc += __shfl_xor(dacc, 32);
  #pragma unroll
  for(int r=0;r<4;r++){
    int ql = gg*4 + r;
    float dn = __shfl(dacc, ql);
    int qg = qblk*64 + w*16 + ql;
    float mq = (float)mask[b*NL + qg];
    float sc = mq / dn;
    short* op = heads + ((size_t)(b*NL + qg))*(NHH*NDK) + h*NDK;
    op[lq]      = bf16s(o0[r]*sc);
    op[16 + lq] = bf16s(o1[r]*sc);
  }
}

extern "C" void kernel_launch(void* const* d_in, const int* in_sizes, int n_in,
                              void* d_out, int out_size, void* d_ws, size_t ws_size,
                              hipStream_t stream){
  const float* x    = (const float*)d_in[0];
  const int*   mask = (const int*)d_in[1];
  const float* dw_w = (const float*)d_in[2];
  const float* dw_b = (const float*)d_in[3];
  const float* pw_w = (const float*)d_in[4];
  const float* pw_b = (const float*)d_in[5];
  const float* ln_g = (const float*)d_in[6];
  const float* ln_b = (const float*)d_in[7];
  const float* Wq   = (const float*)d_in[8];
  const float* Wk   = (const float*)d_in[9];
  const float* Wv   = (const float*)d_in[10];
  const float* Wo   = (const float*)d_in[11];
  const float* fc_w = (const float*)d_in[12];
  const float* fc_b = (const float*)d_in[13];

  float* ws    = (float*)d_ws;
  float* stats = ws;                         // 98304 floats
  float* R     = ws + 98304;                 // 4194304 floats, [b][l][d] fp32
  short* Yb    = (short*)(ws + 4292608);     // 4194304 bf16 (dwconv out / heads)
  short* Qb    = (short*)(ws + 6389760);     // 4194304 bf16
  short* Kb    = (short*)(ws + 8486912);
  short* Vb    = (short*)(ws + 10584064);
  short* gT    = (short*)(ws + 12681216);    // 6*262144 bf16
  short* bT    = (short*)(ws + 13467648);
  short* Wpwb  = (short*)(ws + 14254080);    // 4*65536
  short* Wfcb  = (short*)(ws + 14385152);    // 65536
  short* Wob   = (short*)(ws + 14417920);
  short* Wqb   = (short*)(ws + 14450688);
  short* Wkb   = (short*)(ws + 14483456);
  short* Wvb   = (short*)(ws + 14516224);

  hipMemsetAsync(stats, 0, 98304*sizeof(float), stream);
  k_wcvt<<<256,256,0,stream>>>(pw_w, Wpwb);   // 4*65536 = 262144 elems
  k_wcvt<<<64,256,0,stream>>>(fc_w, Wfcb);
  k_wtr <<<256,256,0,stream>>>(Wo, Wob);
  k_wqkv<<<256,256,0,stream>>>(Wq, Wqb);
  k_wqkv<<<256,256,0,stream>>>(Wk, Wkb);
  k_wqkv<<<256,256,0,stream>>>(Wv, Wvb);
  k_gbt <<<768,256,0,stream>>>(ln_g, ln_b, gT, bT);
  k_posaddT<<<1024,256,0,stream>>>(x, R, stats);
  for(int i=0;i<NCONV;i++){
    k_dwconvT<<<16384,256,0,stream>>>(R, gT + (size_t)i*NPB, bT + (size_t)i*NPB,
                                      dw_w + i*ND*NKW, dw_b + i*ND, stats, Yb, i);
    k_pw<<<1024,256,0,stream>>>(Yb, Wpwb + (size_t)i*65536, pw_b + i*ND, R, stats, i+1);
  }
  k_qk<<<1024,256,0,stream>>>(R, gT + (size_t)4*NPB, bT + (size_t)4*NPB, stats, Wqb, Qb);
  k_qk<<<1024,256,0,stream>>>(R, gT + (size_t)4*NPB, bT + (size_t)4*NPB, stats, Wkb, Kb);
  k_v <<<1024,256,0,stream>>>(R, gT + (size_t)4*NPB, bT + (size_t)4*NPB, stats, Wvb, Vb);
  k_attn<<<2048,256,0,stream>>>(Qb, Kb, Vb, mask, Yb);
  k_wo<<<1024,256,0,stream>>>(Yb, Wob, R, stats);
  k_fc<<<1024,256,0,stream>>>(R, gT + (size_t)5*NPB, bT + (size_t)5*NPB, stats, Wfcb, fc_b, (float*)d_out);
}

// Round 4
// 313.193 us; speedup vs baseline: 4.8034x; 1.5041x over previous
//
#include <hip/hip_runtime.h>
#include <hip/hip_bf16.h>

#define NB 16
#define ND 256
#define NL 1024
#define NHH 8
#define NDK 32
#define NKW 7
#define NCONV 4
#define NPB (ND*NL)

constexpr float LN_EPS = 1e-5f;

typedef __attribute__((ext_vector_type(4))) float f32x4;
typedef __attribute__((ext_vector_type(4))) short bf16x4;
typedef __attribute__((ext_vector_type(8))) short bf16x8;

__device__ __forceinline__ short bf16s(float f){   // RNE via HW conversion (pairs into cvt_pk)
  return (short)__builtin_bit_cast(unsigned short, __float2bfloat16(f));
}
__device__ __forceinline__ float b2f(short s){
  return __builtin_bit_cast(float, ((unsigned)(unsigned short)s) << 16);
}

// ---------------- LN stats: 8 bins x 128B apart per (slot,b) ----------------
__device__ __forceinline__ void ln_ab(const float* st, int slot, int b, float& mean, float& rstd){
  float s = 0.f, ss = 0.f;
  #pragma unroll
  for(int bin=0;bin<8;bin++){
    const float* p = st + ((size_t)((slot*NB+b)*8+bin))*32;
    s += p[0]; ss += p[1];
  }
  mean = s * (1.0f/NPB);
  float var = ss * (1.0f/NPB) - mean*mean;
  rstd = rsqrtf(var + LN_EPS);
}

__device__ __forceinline__ void stats_reduce(float s, float ss, float* stats, int slot, int b, int bin){
  __shared__ float red[8];
  #pragma unroll
  for(int o=32;o>0;o>>=1){ s += __shfl_down(s,o); ss += __shfl_down(ss,o); }
  int lane = threadIdx.x & 63, w = threadIdx.x >> 6;
  if(lane==0){ red[w*2]=s; red[w*2+1]=ss; }
  __syncthreads();
  if(threadIdx.x==0){
    float* p = stats + ((size_t)((slot*NB+b)*8+bin))*32;
    atomicAdd(&p[0], red[0]+red[2]+red[4]+red[6]);
    atomicAdd(&p[1], red[1]+red[3]+red[5]+red[7]);
  }
}

// ---------------- one-shot prep: weight converts + transposes + pos table ----------------
__global__ __launch_bounds__(256) void k_prep(const float* __restrict__ pw_w, const float* __restrict__ fc_w,
    const float* __restrict__ Wo, const float* __restrict__ Wq, const float* __restrict__ Wk,
    const float* __restrict__ Wv, const float* __restrict__ g, const float* __restrict__ btab,
    short* __restrict__ Wpwb, short* __restrict__ Wfcb, short* __restrict__ Wob, short* __restrict__ Wcat,
    short* __restrict__ gT, short* __restrict__ bT, float* __restrict__ postab){
  __shared__ float T[64][65];
  int blk = blockIdx.x, tid = threadIdx.x;
  if(blk < 256){                     // pw_w -> bf16 (262144)
    int idx = blk*1024 + tid*4;
    f32x4 v = *(const f32x4*)(pw_w + idx);
    bf16x4 o;
    #pragma unroll
    for(int j=0;j<4;j++) o[j] = bf16s(v[j]);
    *(bf16x4*)(Wpwb + idx) = o;
  } else if(blk < 320){              // fc_w -> bf16 (65536)
    int idx = (blk-256)*1024 + tid*4;
    f32x4 v = *(const f32x4*)(fc_w + idx);
    bf16x4 o;
    #pragma unroll
    for(int j=0;j<4;j++) o[j] = bf16s(v[j]);
    *(bf16x4*)(Wfcb + idx) = o;
  } else if(blk < 384){              // Wo[d][e] -> bf16 [e][d]
    int idx = (blk-320)*1024 + tid*4;
    int e = idx >> 8;
    bf16x4 o;
    #pragma unroll
    for(int j=0;j<4;j++){ int d = (idx+j)&255; o[j] = bf16s(Wo[d*ND + e]); }
    *(bf16x4*)(Wob + idx) = o;
  } else if(blk < 576){              // Wq/Wk/Wv -> Wcat[(seg*256+h*32+k)][d]
    int idx = (blk-384)*1024 + tid*4;
    int og = idx >> 8, d = idx & 255;
    int seg = og >> 8, o = og & 255, h = o >> 5, k = o & 31;
    const float* W = (seg==0) ? Wq : ((seg==1) ? Wk : Wv);
    bf16x4 ov;
    #pragma unroll
    for(int j=0;j<4;j++) ov[j] = bf16s(W[((size_t)(h*ND + d + j))*NDK + k]);
    *(bf16x4*)(Wcat + idx) = ov;
  } else if(blk < 832){              // pos table [d][l]
    int d = blk - 576;
    int l = tid*4;
    const float LN1E4_OVER_D = 9.210340371976184f / (float)ND;
    float freq, phase;
    if((d & 1) == 0){ freq =  __expf(-(float)d*LN1E4_OVER_D);      phase = 0.f; }
    else            { freq = -__expf((1.f-(float)d)*LN1E4_OVER_D); phase = 1.5707963267948966f; }
    f32x4 o;
    #pragma unroll
    for(int j=0;j<4;j++) o[j] = sinf((float)(l+j)*freq + phase);
    *(f32x4*)(postab + ((size_t)d<<10) + l) = o;
  } else {                           // ln_g/ln_b [slot][d][l] -> bf16 [slot][l][d]
    int blk2 = blk - 832;
    int which = blk2 >> 6;
    int tile = blk2 & 63;
    int d0 = (tile & 3) << 6, l0 = (tile >> 2) << 6;
    const float* src = (which < 6) ? (g + (size_t)which*NPB) : (btab + (size_t)(which-6)*NPB);
    short* dst = (which < 6) ? (gT + (size_t)which*NPB) : (bT + (size_t)(which-6)*NPB);
    for(int i=tid;i<1024;i+=256){
      int dd = i>>4, l4 = i&15;
      f32x4 v = *(const f32x4*)(src + (size_t)(d0+dd)*NL + l0 + l4*4);
      #pragma unroll
      for(int j=0;j<4;j++) T[dd][l4*4+j] = v[j];
    }
    __syncthreads();
    for(int i=tid;i<1024;i+=256){
      int ll = i>>4, d4 = i&15;
      bf16x4 o;
      #pragma unroll
      for(int j=0;j<4;j++) o[j] = bf16s(T[d4*4+j][ll]);
      *(bf16x4*)(dst + (size_t)(l0+ll)*ND + d0 + d4*4) = o;
    }
  }
}

// ---------------- x + pos -> R_T [b][l][d] fp32, stats slot 0 ----------------
__global__ __launch_bounds__(256) void k_posadd(const float* __restrict__ x, const float* __restrict__ postab,
                                                float* __restrict__ R, float* __restrict__ stats){
  int blk = blockIdx.x;
  int lt = blk & 15, dt = (blk>>4)&3, b = blk>>6;
  int l0 = lt*64, d0 = dt*64;
  __shared__ float T[64][65];
  int tid = threadIdx.x;
  float s=0.f, ss=0.f;
  for(int i=tid;i<1024;i+=256){
    int dd = i>>4, l4 = i&15;
    int d = d0+dd;
    f32x4 xv = *(const f32x4*)(x + ((size_t)(b*ND+d)<<10) + l0 + l4*4);
    f32x4 pv = *(const f32x4*)(postab + ((size_t)d<<10) + l0 + l4*4);
    #pragma unroll
    for(int j=0;j<4;j++){
      float v = xv[j] + pv[j];
      T[dd][l4*4+j] = v;
      s += v; ss += v*v;
    }
  }
  __syncthreads();
  for(int i=tid;i<1024;i+=256){
    int ll = i>>4, d4 = i&15;
    f32x4 o;
    #pragma unroll
    for(int j=0;j<4;j++) o[j] = T[d4*4+j][ll];
    *(f32x4*)(R + ((size_t)(b*NL+l0+ll)<<8) + d0 + d4*4) = o;
  }
  stats_reduce(s, ss, stats, 0, b, blk & 7);
}

// ---------------- depthwise conv, vectorized 4d x 4l per thread ----------------
__global__ __launch_bounds__(256) void k_dwconvT(const float* __restrict__ R, const short* __restrict__ gT,
                                                 const short* __restrict__ bT, const float* __restrict__ w7,
                                                 const float* __restrict__ db, const float* __restrict__ stats,
                                                 short* __restrict__ Y, int slot){
  int blk = blockIdx.x;               // b*64 + lblk
  int lblk = blk & 63, b = blk >> 6;
  int tid = threadIdx.x;
  __shared__ float wLds[NKW][ND];
  __shared__ float dbLds[ND];
  for(int i=tid;i<ND*NKW;i+=256){ int d=i/NKW, q=i-d*NKW; wLds[q][d] = w7[i]; }
  dbLds[tid] = db[tid];
  float mean, rstd; ln_ab(stats, slot, b, mean, rstd);
  float mr = mean*rstd;
  __syncthreads();
  int d0 = (tid & 63)*4;
  int l0 = lblk*16 + (tid >> 6)*4;
  f32x4 ln[10];
  #pragma unroll
  for(int i=0;i<10;i++){
    int lp = l0 - 3 + i;
    if(lp >= 0 && lp < NL){
      f32x4 v = *(const f32x4*)(R + ((size_t)(b*NL+lp)<<8) + d0);
      bf16x4 gv = *(const bf16x4*)(gT + ((size_t)lp<<8) + d0);
      bf16x4 bv = *(const bf16x4*)(bT + ((size_t)lp<<8) + d0);
      f32x4 t;
      #pragma unroll
      for(int j=0;j<4;j++) t[j] = (v[j]*rstd - mr)*b2f(gv[j]) + b2f(bv[j]);
      ln[i] = t;
    } else ln[i] = (f32x4){0.f,0.f,0.f,0.f};
  }
  f32x4 dbv = *(const f32x4*)(&dbLds[d0]);
  #pragma unroll
  for(int jl=0;jl<4;jl++){
    f32x4 acc = dbv;
    #pragma unroll
    for(int q=0;q<NKW;q++){
      f32x4 wq = *(const f32x4*)(&wLds[q][d0]);
      #pragma unroll
      for(int j=0;j<4;j++) acc[j] += ln[jl+q][j]*wq[j];
    }
    bf16x4 o;
    #pragma unroll
    for(int j=0;j<4;j++) o[j] = bf16s(acc[j]);
    *(bf16x4*)(Y + ((size_t)(b*NL + l0 + jl)<<8) + d0) = o;
  }
}

// ---------------- shared MFMA GEMM pieces ----------------
__device__ __forceinline__ void stage_rows_bf16(short* dst, const short* src, int tid, int c){
  for(int i=tid;i<1024;i+=256){
    int rr = i>>4, kk = i&15;
    bf16x8 w = *(const bf16x8*)(src + (size_t)rr*ND + c*128 + kk*8);
    *(bf16x8*)((char*)dst + rr*256 + ((kk*16) ^ ((rr&7)<<4))) = w;
  }
}
__device__ __forceinline__ void stage_act_ln(short* dst, const float* src, const short* g, const short* bt,
                                             float mean, float rstd, int tid, int c){
  float mr = mean*rstd;
  for(int i=tid;i<2048;i+=256){
    int ll = i>>5, kk = i&31;
    size_t off = (size_t)ll*ND + c*128 + kk*4;
    f32x4 v = *(const f32x4*)(src + off);
    bf16x4 gv = *(const bf16x4*)(g + off);
    bf16x4 bv = *(const bf16x4*)(bt + off);
    bf16x4 o;
    #pragma unroll
    for(int j=0;j<4;j++) o[j] = bf16s((v[j]*rstd - mr)*b2f(gv[j]) + b2f(bv[j]));
    *(bf16x4*)((char*)dst + ll*256 + ((kk*8) ^ ((ll&7)<<4))) = o;
  }
}
__device__ __forceinline__ void mfma_core(const short* As, const short* Bs, int wm, int wn,
                                          int lq, int gg, f32x4 acc[2][2]){
  #pragma unroll
  for(int t=0;t<4;t++){
    bf16x8 a[2], bb[2];
    #pragma unroll
    for(int m=0;m<2;m++){
      int row = wm*32 + m*16 + lq;
      a[m] = *(const bf16x8*)((const char*)As + row*256 + ((t*64 + gg*16) ^ ((row&7)<<4)));
    }
    #pragma unroll
    for(int n=0;n<2;n++){
      int row = wn*32 + n*16 + lq;
      bb[n] = *(const bf16x8*)((const char*)Bs + row*256 + ((t*64 + gg*16) ^ ((row&7)<<4)));
    }
    #pragma unroll
    for(int m=0;m<2;m++)
      #pragma unroll
      for(int n=0;n<2;n++)
        acc[m][n] = __builtin_amdgcn_mfma_f32_16x16x32_bf16(a[m], bb[n], acc[m][n], 0,0,0);
  }
}

#define GEMM_PROLOGUE() \
  int blk = blockIdx.x; \
  int lt = blk & 15, et = (blk>>4)&3, b = blk>>6; \
  int l0 = lt*64, e0 = et*64; \
  int tid = threadIdx.x; \
  int w = tid>>6, lane = tid&63, lq = lane&15, gg = lane>>4; \
  int wm = w&1, wn = w>>1; \
  __shared__ short As[8192], Bs[8192]; \
  f32x4 acc[2][2]; \
  acc[0][0]=acc[0][1]=acc[1][0]=acc[1][1] = (f32x4){0.f,0.f,0.f,0.f};

// ---- pw: Yb(bf16) x W -> relu+bias, += R, stats ----
__global__ __launch_bounds__(256) void k_pw(const short* __restrict__ Y, const short* __restrict__ Wb,
                                            const float* __restrict__ bias, float* __restrict__ R,
                                            float* __restrict__ stats, int slot_out){
  GEMM_PROLOGUE();
  const short* Asrc = Y + ((size_t)(b*NL)+l0)*ND;
  const short* Bsrc = Wb + (size_t)e0*ND;
  for(int c=0;c<2;c++){
    __syncthreads();
    stage_rows_bf16(As, Asrc, tid, c);
    stage_rows_bf16(Bs, Bsrc, tid, c);
    __syncthreads();
    mfma_core(As, Bs, wm, wn, lq, gg, acc);
  }
  float s=0.f, ss=0.f;
  #pragma unroll
  for(int n=0;n<2;n++){
    int e = e0 + wn*32 + n*16 + lq;
    float bv = bias[e];
    #pragma unroll
    for(int m=0;m<2;m++){
      #pragma unroll
      for(int r=0;r<4;r++){
        int l = l0 + wm*32 + m*16 + gg*4 + r;
        size_t ix = (size_t)(b*NL+l)*ND + e;
        float v = fmaxf(acc[m][n][r] + bv, 0.f);
        float rr = R[ix] + v;
        R[ix] = rr;
        s += rr; ss += rr*rr;
      }
    }
  }
  stats_reduce(s, ss, stats, slot_out, b, blk & 7);
}

// ---- fused QKV: LN(R) x Wcat -> Qb/Kb bf16 [b][h][l][dk], Vb bf16 V^T [b][h][v][l] ----
__global__ __launch_bounds__(256) void k_qkvf(const float* __restrict__ R, const short* __restrict__ gT,
                                              const short* __restrict__ bT, const float* __restrict__ stats,
                                              const short* __restrict__ Wcat, short* __restrict__ Qb,
                                              short* __restrict__ Kb, short* __restrict__ Vb){
  int blk = blockIdx.x;                 // b*192 + et*16 + lt
  int lt = blk & 15;
  int tmp = blk >> 4;
  int et = tmp % 12, b = tmp / 12;
  int l0 = lt*64, e0g = et*64;
  int seg = et >> 2;                    // 0=Q,1=K,2=V
  int tid = threadIdx.x;
  int w = tid>>6, lane = tid&63, lq = lane&15, gg = lane>>4;
  int wm = w&1, wn = w>>1;
  __shared__ short As[8192], Bs[8192];
  f32x4 acc[2][2];
  acc[0][0]=acc[0][1]=acc[1][0]=acc[1][1] = (f32x4){0.f,0.f,0.f,0.f};
  float mean, rstd; ln_ab(stats, 4, b, mean, rstd);
  const float* Asrc = R + ((size_t)(b*NL)+l0)*ND;
  const short* gs = gT + (size_t)l0*ND;
  const short* bs = bT + (size_t)l0*ND;
  const short* Bsrc = Wcat + (size_t)e0g*ND;
  for(int c=0;c<2;c++){
    __syncthreads();
    stage_act_ln(As, Asrc, gs, bs, mean, rstd, tid, c);
    stage_rows_bf16(Bs, Bsrc, tid, c);
    __syncthreads();
    mfma_core(As, Bs, wm, wn, lq, gg, acc);
  }
  #pragma unroll
  for(int n=0;n<2;n++){
    int eo = (et&3)*64 + wn*32 + n*16 + lq;   // 0..255 within segment
    int h = eo>>5, dk = eo&31;
    if(seg < 2){
      short* outp = (seg==0) ? Qb : Kb;
      #pragma unroll
      for(int m=0;m<2;m++){
        #pragma unroll
        for(int r=0;r<4;r++){
          int l = l0 + wm*32 + m*16 + gg*4 + r;
          outp[((size_t)(b*NHH+h)*NL + l)*NDK + dk] = bf16s(acc[m][n][r]);
        }
      }
    } else {
      #pragma unroll
      for(int m=0;m<2;m++){
        int lb = l0 + wm*32 + m*16 + gg*4;
        bf16x4 pk;
        #pragma unroll
        for(int r=0;r<4;r++) pk[r] = bf16s(acc[m][n][r]);
        *(bf16x4*)(Vb + ((size_t)(b*NHH+h)*NDK + dk)*NL + lb) = pk;
      }
    }
  }
}

// ---------------- MFMA flash attention ----------------
__global__ __launch_bounds__(256) void k_attn(const short* __restrict__ Qb, const short* __restrict__ Kb,
                                              const short* __restrict__ Vt, const int* __restrict__ mask,
                                              short* __restrict__ heads){
  int blk = blockIdx.x;
  int qblk = blk & 15, h = (blk >> 4) & 7, b = blk >> 7;
  int bh = b*NHH + h;
  int tid = threadIdx.x;
  int w = tid >> 6, lane = tid & 63;
  int lq = lane & 15, gg = lane >> 4;

  __shared__ short Ks[64][40];
  __shared__ short Vs[32][72];
  __shared__ short Ps[4][16][40];
  __shared__ float msh[64];

  int qrow = qblk*64 + w*16 + lq;
  bf16x8 qf = *(const bf16x8*)(Qb + ((size_t)bh*NL + qrow)*NDK + gg*8);

  f32x4 zero = {0.f,0.f,0.f,0.f};
  f32x4 o0 = zero, o1 = zero;
  float dacc = 0.f;
  const float scale = 0.17677669529663687f;   // 1/sqrt(32)

  for(int t0=0; t0<NL; t0+=64){
    __syncthreads();
    {
      int key = tid >> 2, c = tid & 3;
      *(bf16x8*)(&Ks[key][c*8]) = *(const bf16x8*)(Kb + ((size_t)bh*NL + t0 + key)*NDK + c*8);
      int v = tid >> 3, ch = tid & 7;
      *(bf16x8*)(&Vs[v][ch*8]) = *(const bf16x8*)(Vt + ((size_t)bh*NDK + v)*NL + t0 + ch*8);
      if(tid < 64) msh[tid] = ((float)mask[b*NL + t0 + tid] - 1.f) * 1e30f;   // additive bias
    }
    __syncthreads();
    #pragma unroll
    for(int sub=0; sub<2; sub++){
      bf16x8 a0 = *(const bf16x8*)(&Ks[sub*32 + lq][gg*8]);
      bf16x8 a1 = *(const bf16x8*)(&Ks[sub*32 + 16 + lq][gg*8]);
      f32x4 c0 = __builtin_amdgcn_mfma_f32_16x16x32_bf16(a0, qf, zero, 0, 0, 0);
      f32x4 c1 = __builtin_amdgcn_mfma_f32_16x16x32_bf16(a1, qf, zero, 0, 0, 0);
      bf16x4 p0, p1;
      #pragma unroll
      for(int r=0;r<4;r++){
        float pv0 = __expf(__builtin_fmaf(c0[r], scale, msh[sub*32 + gg*4 + r]));
        dacc += pv0;
        p0[r] = bf16s(pv0);
        float pv1 = __expf(__builtin_fmaf(c1[r], scale, msh[sub*32 + 16 + gg*4 + r]));
        dacc += pv1;
        p1[r] = bf16s(pv1);
      }
      *(bf16x4*)(&Ps[w][lq][gg*4])      = p0;
      *(bf16x4*)(&Ps[w][lq][16 + gg*4]) = p1;
      bf16x8 pf = *(const bf16x8*)(&Ps[w][lq][gg*8]);
      bf16x8 b0 = *(const bf16x8*)(&Vs[lq][sub*32 + gg*8]);
      bf16x8 b1 = *(const bf16x8*)(&Vs[16 + lq][sub*32 + gg*8]);
      o0 = __builtin_amdgcn_mfma_f32_16x16x32_bf16(pf, b0, o0, 0, 0, 0);
      o1 = __builtin_amdgcn_mfma_f32_16x16x32_bf16(pf, b1, o1, 0, 0, 0);
    }
  }
  dacc += __shfl_xor(dacc, 16);
  dacc += __shfl_xor(dacc, 32);
  #pragma unroll
  for(int r=0;r<4;r++){
    int ql = gg*4 + r;
    float dn = __shfl(dacc, ql);
    int qg = qblk*64 + w*16 + ql;
    float mq = (float)mask[b*NL + qg];
    float sc = mq / dn;
    short* op = heads + ((size_t)(b*NL + qg))*(NHH*NDK) + h*NDK;
    op[lq]      = bf16s(o0[r]*sc);
    op[16 + lq] = bf16s(o1[r]*sc);
  }
}

// ---- wo: heads(bf16) x Wo^T -> += R, stats slot 5 ----
__global__ __launch_bounds__(256) void k_wo(const short* __restrict__ H, const short* __restrict__ Wb,
                                            float* __restrict__ R, float* __restrict__ stats){
  GEMM_PROLOGUE();
  const short* Asrc = H + ((size_t)(b*NL)+l0)*ND;
  const short* Bsrc = Wb + (size_t)e0*ND;
  for(int c=0;c<2;c++){
    __syncthreads();
    stage_rows_bf16(As, Asrc, tid, c);
    stage_rows_bf16(Bs, Bsrc, tid, c);
    __syncthreads();
    mfma_core(As, Bs, wm, wn, lq, gg, acc);
  }
  float s=0.f, ss=0.f;
  #pragma unroll
  for(int n=0;n<2;n++){
    int e = e0 + wn*32 + n*16 + lq;
    #pragma unroll
    for(int m=0;m<2;m++){
      #pragma unroll
      for(int r=0;r<4;r++){
        int l = l0 + wm*32 + m*16 + gg*4 + r;
        size_t ix = (size_t)(b*NL+l)*ND + e;
        float rr = R[ix] + acc[m][n][r];
        R[ix] = rr;
        s += rr; ss += rr*rr;
      }
    }
  }
  stats_reduce(s, ss, stats, 5, b, blk & 7);
}

// ---- fc: LN5(R) x fc_w -> relu+bias, + R -> d_out [b][e][l] ----
__global__ __launch_bounds__(256) void k_fc(const float* __restrict__ R, const short* __restrict__ gT,
                                            const short* __restrict__ bT, const float* __restrict__ stats,
                                            const short* __restrict__ Wb, const float* __restrict__ bias,
                                            float* __restrict__ out){
  GEMM_PROLOGUE();
  float mean, rstd; ln_ab(stats, 5, b, mean, rstd);
  const float* Asrc = R + ((size_t)(b*NL)+l0)*ND;
  const short* gs = gT + (size_t)l0*ND;
  const short* bs = bT + (size_t)l0*ND;
  const short* Bsrc = Wb + (size_t)e0*ND;
  for(int c=0;c<2;c++){
    __syncthreads();
    stage_act_ln(As, Asrc, gs, bs, mean, rstd, tid, c);
    stage_rows_bf16(Bs, Bsrc, tid, c);
    __syncthreads();
    mfma_core(As, Bs, wm, wn, lq, gg, acc);
  }
  #pragma unroll
  for(int n=0;n<2;n++){
    int e = e0 + wn*32 + n*16 + lq;
    float bv = bias[e];
    #pragma unroll
    for(int m=0;m<2;m++){
      int lb = l0 + wm*32 + m*16 + gg*4;
      f32x4 ov;
      #pragma unroll
      for(int r=0;r<4;r++){
        float v = fmaxf(acc[m][n][r] + bv, 0.f);
        ov[r] = v + R[(size_t)(b*NL+lb+r)*ND + e];
      }
      *(f32x4*)(out + (size_t)(b*ND+e)*NL + lb) = ov;
    }
  }
}

extern "C" void kernel_launch(void* const* d_in, const int* in_sizes, int n_in,
                              void* d_out, int out_size, void* d_ws, size_t ws_size,
                              hipStream_t stream){
  const float* x    = (const float*)d_in[0];
  const int*   mask = (const int*)d_in[1];
  const float* dw_w = (const float*)d_in[2];
  const float* dw_b = (const float*)d_in[3];
  const float* pw_w = (const float*)d_in[4];
  const float* pw_b = (const float*)d_in[5];
  const float* ln_g = (const float*)d_in[6];
  const float* ln_b = (const float*)d_in[7];
  const float* Wq   = (const float*)d_in[8];
  const float* Wk   = (const float*)d_in[9];
  const float* Wv   = (const float*)d_in[10];
  const float* Wo   = (const float*)d_in[11];
  const float* fc_w = (const float*)d_in[12];
  const float* fc_b = (const float*)d_in[13];

  float* ws     = (float*)d_ws;
  float* stats  = ws;                          // 98304 floats
  float* postab = ws + 98304;                  // 262144 floats
  float* R      = ws + 360448;                 // 4194304 floats [b][l][d]
  short* Yb     = (short*)(ws + 4554752);      // 4194304 bf16
  short* Qb     = (short*)(ws + 6651904);
  short* Kb     = (short*)(ws + 8749056);
  short* Vb     = (short*)(ws + 10846208);
  short* gT     = (short*)(ws + 12943360);     // 6*262144 bf16
  short* bT     = (short*)(ws + 13729792);
  short* Wpwb   = (short*)(ws + 14516224);     // 262144 bf16
  short* Wfcb   = (short*)(ws + 14647296);     // 65536
  short* Wob    = (short*)(ws + 14680064);     // 65536
  short* Wcat   = (short*)(ws + 14712832);     // 196608

  hipMemsetAsync(stats, 0, 98304*sizeof(float), stream);
  k_prep<<<1600,256,0,stream>>>(pw_w, fc_w, Wo, Wq, Wk, Wv, ln_g, ln_b,
                                Wpwb, Wfcb, Wob, Wcat, gT, bT, postab);
  k_posadd<<<1024,256,0,stream>>>(x, postab, R, stats);
  for(int i=0;i<NCONV;i++){
    k_dwconvT<<<1024,256,0,stream>>>(R, gT + (size_t)i*NPB, bT + (size_t)i*NPB,
                                     dw_w + i*ND*NKW, dw_b + i*ND, stats, Yb, i);
    k_pw<<<1024,256,0,stream>>>(Yb, Wpwb + (size_t)i*65536, pw_b + i*ND, R, stats, i+1);
  }
  k_qkvf<<<3072,256,0,stream>>>(R, gT + (size_t)4*NPB, bT + (size_t)4*NPB, stats, Wcat, Qb, Kb, Vb);
  k_attn<<<2048,256,0,stream>>>(Qb, Kb, Vb, mask, Yb);
  k_wo<<<1024,256,0,stream>>>(Yb, Wob, R, stats);
  k_fc<<<1024,256,0,stream>>>(R, gT + (size_t)5*NPB, bT + (size_t)5*NPB, stats, Wfcb, fc_b, (float*)d_out);
}

// Round 5
// 304.677 us; speedup vs baseline: 4.9376x; 1.0279x over previous
//
#include <hip/hip_runtime.h>
#include <hip/hip_bf16.h>

#define NB 16
#define ND 256
#define NL 1024
#define NHH 8
#define NDK 32
#define NKW 7
#define NCONV 4
#define NPB (ND*NL)

constexpr float LN_EPS = 1e-5f;

typedef __attribute__((ext_vector_type(4))) float f32x4;
typedef __attribute__((ext_vector_type(4))) short bf16x4;
typedef __attribute__((ext_vector_type(8))) short bf16x8;

__device__ __forceinline__ short bf16s(float f){   // RNE via HW conversion (pairs into cvt_pk)
  return (short)__builtin_bit_cast(unsigned short, __float2bfloat16(f));
}
__device__ __forceinline__ float b2f(short s){
  return __builtin_bit_cast(float, ((unsigned)(unsigned short)s) << 16);
}

// ---------------- LN stats: 8 bins x 128B apart per (slot,b) ----------------
__device__ __forceinline__ void ln_ab(const float* st, int slot, int b, float& mean, float& rstd){
  float s = 0.f, ss = 0.f;
  #pragma unroll
  for(int bin=0;bin<8;bin++){
    const float* p = st + ((size_t)((slot*NB+b)*8+bin))*32;
    s += p[0]; ss += p[1];
  }
  mean = s * (1.0f/NPB);
  float var = ss * (1.0f/NPB) - mean*mean;
  rstd = rsqrtf(var + LN_EPS);
}

__device__ __forceinline__ void stats_reduce(float s, float ss, float* stats, int slot, int b, int bin){
  __shared__ float red[8];
  #pragma unroll
  for(int o=32;o>0;o>>=1){ s += __shfl_down(s,o); ss += __shfl_down(ss,o); }
  int lane = threadIdx.x & 63, w = threadIdx.x >> 6;
  if(lane==0){ red[w*2]=s; red[w*2+1]=ss; }
  __syncthreads();
  if(threadIdx.x==0){
    float* p = stats + ((size_t)((slot*NB+b)*8+bin))*32;
    atomicAdd(&p[0], red[0]+red[2]+red[4]+red[6]);
    atomicAdd(&p[1], red[1]+red[3]+red[5]+red[7]);
  }
}

// ---------------- one-shot prep: weight converts + transposes + pos table ----------------
__global__ __launch_bounds__(256) void k_prep(const float* __restrict__ pw_w, const float* __restrict__ fc_w,
    const float* __restrict__ Wo, const float* __restrict__ Wq, const float* __restrict__ Wk,
    const float* __restrict__ Wv, const float* __restrict__ g, const float* __restrict__ btab,
    short* __restrict__ Wpwb, short* __restrict__ Wfcb, short* __restrict__ Wob, short* __restrict__ Wcat,
    short* __restrict__ gT, short* __restrict__ bT, float* __restrict__ postab){
  __shared__ float T[64][65];
  int blk = blockIdx.x, tid = threadIdx.x;
  if(blk < 256){                     // pw_w -> bf16 (262144)
    int idx = blk*1024 + tid*4;
    f32x4 v = *(const f32x4*)(pw_w + idx);
    bf16x4 o;
    #pragma unroll
    for(int j=0;j<4;j++) o[j] = bf16s(v[j]);
    *(bf16x4*)(Wpwb + idx) = o;
  } else if(blk < 320){              // fc_w -> bf16 (65536)
    int idx = (blk-256)*1024 + tid*4;
    f32x4 v = *(const f32x4*)(fc_w + idx);
    bf16x4 o;
    #pragma unroll
    for(int j=0;j<4;j++) o[j] = bf16s(v[j]);
    *(bf16x4*)(Wfcb + idx) = o;
  } else if(blk < 384){              // Wo[d][e] -> bf16 [e][d]
    int idx = (blk-320)*1024 + tid*4;
    int e = idx >> 8;
    bf16x4 o;
    #pragma unroll
    for(int j=0;j<4;j++){ int d = (idx+j)&255; o[j] = bf16s(Wo[d*ND + e]); }
    *(bf16x4*)(Wob + idx) = o;
  } else if(blk < 576){              // Wq/Wk/Wv -> Wcat[(seg*256+h*32+k)][d]
    int idx = (blk-384)*1024 + tid*4;
    int og = idx >> 8, d = idx & 255;
    int seg = og >> 8, o = og & 255, h = o >> 5, k = o & 31;
    const float* W = (seg==0) ? Wq : ((seg==1) ? Wk : Wv);
    bf16x4 ov;
    #pragma unroll
    for(int j=0;j<4;j++) ov[j] = bf16s(W[((size_t)(h*ND + d + j))*NDK + k]);
    *(bf16x4*)(Wcat + idx) = ov;
  } else if(blk < 832){              // pos table [d][l]
    int d = blk - 576;
    int l = tid*4;
    const float LN1E4_OVER_D = 9.210340371976184f / (float)ND;
    float freq, phase;
    if((d & 1) == 0){ freq =  __expf(-(float)d*LN1E4_OVER_D);      phase = 0.f; }
    else            { freq = -__expf((1.f-(float)d)*LN1E4_OVER_D); phase = 1.5707963267948966f; }
    f32x4 o;
    #pragma unroll
    for(int j=0;j<4;j++) o[j] = sinf((float)(l+j)*freq + phase);
    *(f32x4*)(postab + ((size_t)d<<10) + l) = o;
  } else {                           // ln_g/ln_b [slot][d][l] -> bf16 [slot][l][d]
    int blk2 = blk - 832;
    int which = blk2 >> 6;
    int tile = blk2 & 63;
    int d0 = (tile & 3) << 6, l0 = (tile >> 2) << 6;
    const float* src = (which < 6) ? (g + (size_t)which*NPB) : (btab + (size_t)(which-6)*NPB);
    short* dst = (which < 6) ? (gT + (size_t)which*NPB) : (bT + (size_t)(which-6)*NPB);
    for(int i=tid;i<1024;i+=256){
      int dd = i>>4, l4 = i&15;
      f32x4 v = *(const f32x4*)(src + (size_t)(d0+dd)*NL + l0 + l4*4);
      #pragma unroll
      for(int j=0;j<4;j++) T[dd][l4*4+j] = v[j];
    }
    __syncthreads();
    for(int i=tid;i<1024;i+=256){
      int ll = i>>4, d4 = i&15;
      bf16x4 o;
      #pragma unroll
      for(int j=0;j<4;j++) o[j] = bf16s(T[d4*4+j][ll]);
      *(bf16x4*)(dst + (size_t)(l0+ll)*ND + d0 + d4*4) = o;
    }
  }
}

// ---------------- x + pos -> Rb [b][l][d] bf16, stats slot 0 (on rounded values) ----------------
__global__ __launch_bounds__(256) void k_posadd(const float* __restrict__ x, const float* __restrict__ postab,
                                                short* __restrict__ Rb, float* __restrict__ stats){
  int blk = blockIdx.x;
  int lt = blk & 15, dt = (blk>>4)&3, b = blk>>6;
  int l0 = lt*64, d0 = dt*64;
  __shared__ float T[64][65];
  int tid = threadIdx.x;
  for(int i=tid;i<1024;i+=256){
    int dd = i>>4, l4 = i&15;
    int d = d0+dd;
    f32x4 xv = *(const f32x4*)(x + ((size_t)(b*ND+d)<<10) + l0 + l4*4);
    f32x4 pv = *(const f32x4*)(postab + ((size_t)d<<10) + l0 + l4*4);
    #pragma unroll
    for(int j=0;j<4;j++) T[dd][l4*4+j] = xv[j] + pv[j];
  }
  __syncthreads();
  float s=0.f, ss=0.f;
  for(int i=tid;i<1024;i+=256){
    int ll = i>>4, d4 = i&15;
    bf16x4 o;
    #pragma unroll
    for(int j=0;j<4;j++){
      short rs = bf16s(T[d4*4+j][ll]);
      o[j] = rs;
      float rv = b2f(rs);
      s += rv; ss += rv*rv;
    }
    *(bf16x4*)(Rb + ((size_t)(b*NL+l0+ll)<<8) + d0 + d4*4) = o;
  }
  stats_reduce(s, ss, stats, 0, b, blk & 7);
}

// ---------------- depthwise conv, vectorized 4d x 4l per thread, bf16 R ----------------
__global__ __launch_bounds__(256) void k_dwconvT(const short* __restrict__ Rb, const short* __restrict__ gT,
                                                 const short* __restrict__ bT, const float* __restrict__ w7,
                                                 const float* __restrict__ db, const float* __restrict__ stats,
                                                 short* __restrict__ Y, int slot){
  int blk = blockIdx.x;               // b*64 + lblk
  int lblk = blk & 63, b = blk >> 6;
  int tid = threadIdx.x;
  __shared__ float wLds[NKW][ND];
  __shared__ float dbLds[ND];
  for(int i=tid;i<ND*NKW;i+=256){ int d=i/NKW, q=i-d*NKW; wLds[q][d] = w7[i]; }
  dbLds[tid] = db[tid];
  float mean, rstd; ln_ab(stats, slot, b, mean, rstd);
  float mr = mean*rstd;
  __syncthreads();
  int d0 = (tid & 63)*4;
  int l0 = lblk*16 + (tid >> 6)*4;
  f32x4 ln[10];
  #pragma unroll
  for(int i=0;i<10;i++){
    int lp = l0 - 3 + i;
    if(lp >= 0 && lp < NL){
      bf16x4 v = *(const bf16x4*)(Rb + ((size_t)(b*NL+lp)<<8) + d0);
      bf16x4 gv = *(const bf16x4*)(gT + ((size_t)lp<<8) + d0);
      bf16x4 bv = *(const bf16x4*)(bT + ((size_t)lp<<8) + d0);
      f32x4 t;
      #pragma unroll
      for(int j=0;j<4;j++) t[j] = (b2f(v[j])*rstd - mr)*b2f(gv[j]) + b2f(bv[j]);
      ln[i] = t;
    } else ln[i] = (f32x4){0.f,0.f,0.f,0.f};
  }
  f32x4 dbv = *(const f32x4*)(&dbLds[d0]);
  #pragma unroll
  for(int jl=0;jl<4;jl++){
    f32x4 acc = dbv;
    #pragma unroll
    for(int q=0;q<NKW;q++){
      f32x4 wq = *(const f32x4*)(&wLds[q][d0]);
      #pragma unroll
      for(int j=0;j<4;j++) acc[j] += ln[jl+q][j]*wq[j];
    }
    bf16x4 o;
    #pragma unroll
    for(int j=0;j<4;j++) o[j] = bf16s(acc[j]);
    *(bf16x4*)(Y + ((size_t)(b*NL + l0 + jl)<<8) + d0) = o;
  }
}

// ---------------- shared MFMA GEMM pieces ----------------
__device__ __forceinline__ void stage_rows_bf16(short* dst, const short* src, int tid, int c){
  for(int i=tid;i<1024;i+=256){
    int rr = i>>4, kk = i&15;
    bf16x8 w = *(const bf16x8*)(src + (size_t)rr*ND + c*128 + kk*8);
    *(bf16x8*)((char*)dst + rr*256 + ((kk*16) ^ ((rr&7)<<4))) = w;
  }
}
// bf16 activations with LN affine
__device__ __forceinline__ void stage_act_lnb(short* dst, const short* src, const short* g, const short* bt,
                                              float mean, float rstd, int tid, int c){
  float mr = mean*rstd;
  for(int i=tid;i<1024;i+=256){
    int ll = i>>4, kk = i&15;
    size_t off = (size_t)ll*ND + c*128 + kk*8;
    bf16x8 v = *(const bf16x8*)(src + off);
    bf16x8 gv = *(const bf16x8*)(g + off);
    bf16x8 bv = *(const bf16x8*)(bt + off);
    bf16x8 o;
    #pragma unroll
    for(int j=0;j<8;j++) o[j] = bf16s((b2f(v[j])*rstd - mr)*b2f(gv[j]) + b2f(bv[j]));
    *(bf16x8*)((char*)dst + ll*256 + ((kk*16) ^ ((ll&7)<<4))) = o;
  }
}
__device__ __forceinline__ void mfma_core(const short* As, const short* Bs, int wm, int wn,
                                          int lq, int gg, f32x4 acc[2][2]){
  #pragma unroll
  for(int t=0;t<4;t++){
    bf16x8 a[2], bb[2];
    #pragma unroll
    for(int m=0;m<2;m++){
      int row = wm*32 + m*16 + lq;
      a[m] = *(const bf16x8*)((const char*)As + row*256 + ((t*64 + gg*16) ^ ((row&7)<<4)));
    }
    #pragma unroll
    for(int n=0;n<2;n++){
      int row = wn*32 + n*16 + lq;
      bb[n] = *(const bf16x8*)((const char*)Bs + row*256 + ((t*64 + gg*16) ^ ((row&7)<<4)));
    }
    #pragma unroll
    for(int m=0;m<2;m++)
      #pragma unroll
      for(int n=0;n<2;n++)
        acc[m][n] = __builtin_amdgcn_mfma_f32_16x16x32_bf16(a[m], bb[n], acc[m][n], 0,0,0);
  }
}

#define GEMM_PROLOGUE() \
  int blk = blockIdx.x; \
  int lt = blk & 15, et = (blk>>4)&3, b = blk>>6; \
  int l0 = lt*64, e0 = et*64; \
  int tid = threadIdx.x; \
  int w = tid>>6, lane = tid&63, lq = lane&15, gg = lane>>4; \
  int wm = w&1, wn = w>>1; \
  __shared__ short As[8192], Bs[8192]; \
  f32x4 acc[2][2]; \
  acc[0][0]=acc[0][1]=acc[1][0]=acc[1][1] = (f32x4){0.f,0.f,0.f,0.f};

// ---- pw: Yb(bf16) x W -> relu+bias, Rb += , stats ----
__global__ __launch_bounds__(256) void k_pw(const short* __restrict__ Y, const short* __restrict__ Wb,
                                            const float* __restrict__ bias, short* __restrict__ Rb,
                                            float* __restrict__ stats, int slot_out){
  GEMM_PROLOGUE();
  const short* Asrc = Y + ((size_t)(b*NL)+l0)*ND;
  const short* Bsrc = Wb + (size_t)e0*ND;
  for(int c=0;c<2;c++){
    __syncthreads();
    stage_rows_bf16(As, Asrc, tid, c);
    stage_rows_bf16(Bs, Bsrc, tid, c);
    __syncthreads();
    mfma_core(As, Bs, wm, wn, lq, gg, acc);
  }
  float s=0.f, ss=0.f;
  #pragma unroll
  for(int n=0;n<2;n++){
    int e = e0 + wn*32 + n*16 + lq;
    float bv = bias[e];
    #pragma unroll
    for(int m=0;m<2;m++){
      #pragma unroll
      for(int r=0;r<4;r++){
        int l = l0 + wm*32 + m*16 + gg*4 + r;
        size_t ix = (size_t)(b*NL+l)*ND + e;
        float v = fmaxf(acc[m][n][r] + bv, 0.f);
        float rr = b2f(Rb[ix]) + v;
        short rs = bf16s(rr);
        Rb[ix] = rs;
        float r2 = b2f(rs);
        s += r2; ss += r2*r2;
      }
    }
  }
  stats_reduce(s, ss, stats, slot_out, b, blk & 7);
}

// ---- fused QKV: LN(Rb) x Wcat -> Qb/Kb bf16 [b][h][l][dk], Vb bf16 V^T [b][h][v][l] ----
__global__ __launch_bounds__(256) void k_qkvf(const short* __restrict__ Rb, const short* __restrict__ gT,
                                              const short* __restrict__ bT, const float* __restrict__ stats,
                                              const short* __restrict__ Wcat, short* __restrict__ Qb,
                                              short* __restrict__ Kb, short* __restrict__ Vb){
  int blk = blockIdx.x;                 // b*192 + et*16 + lt
  int lt = blk & 15;
  int tmp = blk >> 4;
  int et = tmp % 12, b = tmp / 12;
  int l0 = lt*64, e0g = et*64;
  int seg = et >> 2;                    // 0=Q,1=K,2=V
  int tid = threadIdx.x;
  int w = tid>>6, lane = tid&63, lq = lane&15, gg = lane>>4;
  int wm = w&1, wn = w>>1;
  __shared__ short As[8192], Bs[8192];
  f32x4 acc[2][2];
  acc[0][0]=acc[0][1]=acc[1][0]=acc[1][1] = (f32x4){0.f,0.f,0.f,0.f};
  float mean, rstd; ln_ab(stats, 4, b, mean, rstd);
  const short* Asrc = Rb + ((size_t)(b*NL)+l0)*ND;
  const short* gs = gT + (size_t)l0*ND;
  const short* bs = bT + (size_t)l0*ND;
  const short* Bsrc = Wcat + (size_t)e0g*ND;
  for(int c=0;c<2;c++){
    __syncthreads();
    stage_act_lnb(As, Asrc, gs, bs, mean, rstd, tid, c);
    stage_rows_bf16(Bs, Bsrc, tid, c);
    __syncthreads();
    mfma_core(As, Bs, wm, wn, lq, gg, acc);
  }
  #pragma unroll
  for(int n=0;n<2;n++){
    int eo = (et&3)*64 + wn*32 + n*16 + lq;   // 0..255 within segment
    int h = eo>>5, dk = eo&31;
    if(seg < 2){
      short* outp = (seg==0) ? Qb : Kb;
      #pragma unroll
      for(int m=0;m<2;m++){
        #pragma unroll
        for(int r=0;r<4;r++){
          int l = l0 + wm*32 + m*16 + gg*4 + r;
          outp[((size_t)(b*NHH+h)*NL + l)*NDK + dk] = bf16s(acc[m][n][r]);
        }
      }
    } else {
      #pragma unroll
      for(int m=0;m<2;m++){
        int lb = l0 + wm*32 + m*16 + gg*4;
        bf16x4 pk;
        #pragma unroll
        for(int r=0;r<4;r++) pk[r] = bf16s(acc[m][n][r]);
        *(bf16x4*)(Vb + ((size_t)(b*NHH+h)*NDK + dk)*NL + lb) = pk;
      }
    }
  }
}

// ---------------- MFMA flash attention; XCD-swizzled; denom via ones-MFMA ----------------
__global__ __launch_bounds__(256) void k_attn(const short* __restrict__ Qb, const short* __restrict__ Kb,
                                              const short* __restrict__ Vt, const int* __restrict__ mask,
                                              short* __restrict__ heads){
  int blk = blockIdx.x;
  // 16 qblks of one (b,h) are 128 apart -> same XCD (128 % 8 == 0) -> K/V stays in that L2
  int qblk = blk >> 7, bh = blk & 127;
  int b = bh >> 3, h = bh & 7;
  int tid = threadIdx.x;
  int w = tid >> 6, lane = tid & 63;
  int lq = lane & 15, gg = lane >> 4;

  __shared__ short Ks[64][40];
  __shared__ short Vs[32][72];
  __shared__ short Ps[4][16][40];
  __shared__ float msh[64];

  int qrow = qblk*64 + w*16 + lq;
  bf16x8 qf = *(const bf16x8*)(Qb + ((size_t)bh*NL + qrow)*NDK + gg*8);

  bf16x8 ones;
  #pragma unroll
  for(int j=0;j<8;j++) ones[j] = (short)0x3F80;   // 1.0bf16

  f32x4 zero = {0.f,0.f,0.f,0.f};
  f32x4 o0 = zero, o1 = zero, o2 = zero;          // o2 = row denominators
  const float scale = 0.17677669529663687f;       // 1/sqrt(32)

  for(int t0=0; t0<NL; t0+=64){
    __syncthreads();
    {
      int key = tid >> 2, c = tid & 3;
      *(bf16x8*)(&Ks[key][c*8]) = *(const bf16x8*)(Kb + ((size_t)bh*NL + t0 + key)*NDK + c*8);
      int v = tid >> 3, ch = tid & 7;
      *(bf16x8*)(&Vs[v][ch*8]) = *(const bf16x8*)(Vt + ((size_t)bh*NDK + v)*NL + t0 + ch*8);
      if(tid < 64) msh[tid] = ((float)mask[b*NL + t0 + tid] - 1.f) * 1e30f;   // additive bias
    }
    __syncthreads();
    #pragma unroll
    for(int sub=0; sub<2; sub++){
      bf16x8 a0 = *(const bf16x8*)(&Ks[sub*32 + lq][gg*8]);
      bf16x8 a1 = *(const bf16x8*)(&Ks[sub*32 + 16 + lq][gg*8]);
      f32x4 c0 = __builtin_amdgcn_mfma_f32_16x16x32_bf16(a0, qf, zero, 0, 0, 0);
      f32x4 c1 = __builtin_amdgcn_mfma_f32_16x16x32_bf16(a1, qf, zero, 0, 0, 0);
      bf16x4 p0, p1;
      #pragma unroll
      for(int r=0;r<4;r++){
        float pv0 = __expf(__builtin_fmaf(c0[r], scale, msh[sub*32 + gg*4 + r]));
        p0[r] = bf16s(pv0);
        float pv1 = __expf(__builtin_fmaf(c1[r], scale, msh[sub*32 + 16 + gg*4 + r]));
        p1[r] = bf16s(pv1);
      }
      *(bf16x4*)(&Ps[w][lq][gg*4])      = p0;
      *(bf16x4*)(&Ps[w][lq][16 + gg*4]) = p1;
      bf16x8 pf = *(const bf16x8*)(&Ps[w][lq][gg*8]);
      bf16x8 b0 = *(const bf16x8*)(&Vs[lq][sub*32 + gg*8]);
      bf16x8 b1 = *(const bf16x8*)(&Vs[16 + lq][sub*32 + gg*8]);
      o0 = __builtin_amdgcn_mfma_f32_16x16x32_bf16(pf, b0, o0, 0, 0, 0);
      o1 = __builtin_amdgcn_mfma_f32_16x16x32_bf16(pf, b1, o1, 0, 0, 0);
      o2 = __builtin_amdgcn_mfma_f32_16x16x32_bf16(pf, ones, o2, 0, 0, 0);
    }
  }
  #pragma unroll
  for(int r=0;r<4;r++){
    int ql = gg*4 + r;
    int qg = qblk*64 + w*16 + ql;
    float mq = (float)mask[b*NL + qg];
    float sc = mq / o2[r];
    short* op = heads + ((size_t)(b*NL + qg))*(NHH*NDK) + h*NDK;
    op[lq]      = bf16s(o0[r]*sc);
    op[16 + lq] = bf16s(o1[r]*sc);
  }
}

// ---- wo: heads(bf16) x Wo^T -> Rb +=, stats slot 5 ----
__global__ __launch_bounds__(256) void k_wo(const short* __restrict__ H, const short* __restrict__ Wb,
                                            short* __restrict__ Rb, float* __restrict__ stats){
  GEMM_PROLOGUE();
  const short* Asrc = H + ((size_t)(b*NL)+l0)*ND;
  const short* Bsrc = Wb + (size_t)e0*ND;
  for(int c=0;c<2;c++){
    __syncthreads();
    stage_rows_bf16(As, Asrc, tid, c);
    stage_rows_bf16(Bs, Bsrc, tid, c);
    __syncthreads();
    mfma_core(As, Bs, wm, wn, lq, gg, acc);
  }
  float s=0.f, ss=0.f;
  #pragma unroll
  for(int n=0;n<2;n++){
    int e = e0 + wn*32 + n*16 + lq;
    #pragma unroll
    for(int m=0;m<2;m++){
      #pragma unroll
      for(int r=0;r<4;r++){
        int l = l0 + wm*32 + m*16 + gg*4 + r;
        size_t ix = (size_t)(b*NL+l)*ND + e;
        float rr = b2f(Rb[ix]) + acc[m][n][r];
        short rs = bf16s(rr);
        Rb[ix] = rs;
        float r2 = b2f(rs);
        s += r2; ss += r2*r2;
      }
    }
  }
  stats_reduce(s, ss, stats, 5, b, blk & 7);
}

// ---- fc: LN5(Rb) x fc_w -> relu+bias, + Rb -> d_out [b][e][l] fp32 ----
__global__ __launch_bounds__(256) void k_fc(const short* __restrict__ Rb, const short* __restrict__ gT,
                                            const short* __restrict__ bT, const float* __restrict__ stats,
                                            const short* __restrict__ Wb, const float* __restrict__ bias,
                                            float* __restrict__ out){
  GEMM_PROLOGUE();
  float mean, rstd; ln_ab(stats, 5, b, mean, rstd);
  const short* Asrc = Rb + ((size_t)(b*NL)+l0)*ND;
  const short* gs = gT + (size_t)l0*ND;
  const short* bs = bT + (size_t)l0*ND;
  const short* Bsrc = Wb + (size_t)e0*ND;
  for(int c=0;c<2;c++){
    __syncthreads();
    stage_act_lnb(As, Asrc, gs, bs, mean, rstd, tid, c);
    stage_rows_bf16(Bs, Bsrc, tid, c);
    __syncthreads();
    mfma_core(As, Bs, wm, wn, lq, gg, acc);
  }
  #pragma unroll
  for(int n=0;n<2;n++){
    int e = e0 + wn*32 + n*16 + lq;
    float bv = bias[e];
    #pragma unroll
    for(int m=0;m<2;m++){
      int lb = l0 + wm*32 + m*16 + gg*4;
      f32x4 ov;
      #pragma unroll
      for(int r=0;r<4;r++){
        float v = fmaxf(acc[m][n][r] + bv, 0.f);
        ov[r] = v + b2f(Rb[(size_t)(b*NL+lb+r)*ND + e]);
      }
      *(f32x4*)(out + (size_t)(b*ND+e)*NL + lb) = ov;
    }
  }
}

extern "C" void kernel_launch(void* const* d_in, const int* in_sizes, int n_in,
                              void* d_out, int out_size, void* d_ws, size_t ws_size,
                              hipStream_t stream){
  const float* x    = (const float*)d_in[0];
  const int*   mask = (const int*)d_in[1];
  const float* dw_w = (const float*)d_in[2];
  const float* dw_b = (const float*)d_in[3];
  const float* pw_w = (const float*)d_in[4];
  const float* pw_b = (const float*)d_in[5];
  const float* ln_g = (const float*)d_in[6];
  const float* ln_b = (const float*)d_in[7];
  const float* Wq   = (const float*)d_in[8];
  const float* Wk   = (const float*)d_in[9];
  const float* Wv   = (const float*)d_in[10];
  const float* Wo   = (const float*)d_in[11];
  const float* fc_w = (const float*)d_in[12];
  const float* fc_b = (const float*)d_in[13];

  float* ws     = (float*)d_ws;
  float* stats  = ws;                          // 98304 floats
  float* postab = ws + 98304;                  // 262144 floats
  short* Rb     = (short*)(ws + 360448);       // 4194304 bf16 [b][l][d]
  short* Yb     = (short*)(ws + 2457600);      // 4194304 bf16
  short* Qb     = (short*)(ws + 4554752);
  short* Kb     = (short*)(ws + 6651904);
  short* Vb     = (short*)(ws + 8749056);
  short* gT     = (short*)(ws + 10846208);     // 6*262144 bf16
  short* bT     = (short*)(ws + 11632640);
  short* Wpwb   = (short*)(ws + 12419072);     // 262144 bf16
  short* Wfcb   = (short*)(ws + 12550144);     // 65536
  short* Wob    = (short*)(ws + 12582912);     // 65536
  short* Wcat   = (short*)(ws + 12615680);     // 196608

  hipMemsetAsync(stats, 0, 98304*sizeof(float), stream);
  k_prep<<<1600,256,0,stream>>>(pw_w, fc_w, Wo, Wq, Wk, Wv, ln_g, ln_b,
                                Wpwb, Wfcb, Wob, Wcat, gT, bT, postab);
  k_posadd<<<1024,256,0,stream>>>(x, postab, Rb, stats);
  for(int i=0;i<NCONV;i++){
    k_dwconvT<<<1024,256,0,stream>>>(Rb, gT + (size_t)i*NPB, bT + (size_t)i*NPB,
                                     dw_w + i*ND*NKW, dw_b + i*ND, stats, Yb, i);
    k_pw<<<1024,256,0,stream>>>(Yb, Wpwb + (size_t)i*65536, pw_b + i*ND, Rb, stats, i+1);
  }
  k_qkvf<<<3072,256,0,stream>>>(Rb, gT + (size_t)4*NPB, bT + (size_t)4*NPB, stats, Wcat, Qb, Kb, Vb);
  k_attn<<<2048,256,0,stream>>>(Qb, Kb, Vb, mask, Yb);
  k_wo<<<1024,256,0,stream>>>(Yb, Wob, Rb, stats);
  k_fc<<<1024,256,0,stream>>>(Rb, gT + (size_t)5*NPB, bT + (size_t)5*NPB, stats, Wfcb, fc_b, (float*)d_out);
}